// Round 1
// baseline (1724.744 us; speedup 1.0000x reference)
//
#include <hip/hip_runtime.h>
#include <hip/hip_bf16.h>

#define NH1 4
#define C1V 16
#define HC1 64
#define C2V 32
#define GV 64
#define NCLSV 10

__device__ __forceinline__ unsigned fenc(float f) {
    unsigned u = __float_as_uint(f);
    return (u & 0x80000000u) ? ~u : (u | 0x80000000u);
}
__device__ __forceinline__ float fdec(unsigned u) {
    unsigned b = (u & 0x80000000u) ? (u & 0x7FFFFFFFu) : ~u;
    return __uint_as_float(b);
}
__device__ __forceinline__ float lrelu(float v) { return v > 0.f ? v : 0.2f * v; }
__device__ __forceinline__ float eluf(float v) { return v > 0.f ? v : expf(v) - 1.f; }

__global__ void zero_kernel(float* p, size_t n) {
    size_t i = (size_t)blockIdx.x * blockDim.x + threadIdx.x;
    size_t stride = (size_t)gridDim.x * blockDim.x;
    for (; i < n; i += stride) p[i] = 0.f;
}

__global__ __launch_bounds__(256) void gemm1_kernel(
    const float* __restrict__ x, const float* __restrict__ W1,
    const float* __restrict__ as_w, const float* __restrict__ ad_w,
    float* __restrict__ h1, float* __restrict__ as1, float* __restrict__ ad1, int N) {
    __shared__ float xs[16 * 256];
    int b0 = blockIdx.x * 16;
    for (int idx = threadIdx.x; idx < 16 * 256; idx += 256) {
        int node = b0 + (idx >> 8);
        xs[idx] = (node < N) ? x[(size_t)node * 256 + (idx & 255)] : 0.f;
    }
    __syncthreads();
    int lane = threadIdx.x & 63;
    int w = threadIdx.x >> 6;
    float acc0 = 0.f, acc1 = 0.f, acc2 = 0.f, acc3 = 0.f;
    const float* xw = xs + w * 4 * 256;
    for (int k = 0; k < 256; ++k) {
        float wv = W1[k * 64 + lane];
        acc0 += xw[k] * wv;
        acc1 += xw[256 + k] * wv;
        acc2 += xw[512 + k] * wv;
        acc3 += xw[768 + k] * wv;
    }
    float asw = as_w[lane], adw = ad_w[lane];
    float accs[4] = {acc0, acc1, acc2, acc3};
    for (int i = 0; i < 4; ++i) {
        int n = b0 + w * 4 + i;
        if (n >= N) continue;
        float a = accs[i];
        h1[(size_t)n * 64 + lane] = a;
        float vs = a * asw, vd = a * adw;
        vs += __shfl_xor(vs, 1); vs += __shfl_xor(vs, 2);
        vs += __shfl_xor(vs, 4); vs += __shfl_xor(vs, 8);
        vd += __shfl_xor(vd, 1); vd += __shfl_xor(vd, 2);
        vd += __shfl_xor(vd, 4); vd += __shfl_xor(vd, 8);
        if ((lane & 15) == 0) {
            as1[n * 4 + (lane >> 4)] = vs;
            ad1[n * 4 + (lane >> 4)] = vd;
        }
    }
}

__global__ void max1_kernel(const int* __restrict__ ei, int E, int EE,
                            const float* __restrict__ as1, const float* __restrict__ ad1,
                            unsigned* __restrict__ m1u) {
    int idx = blockIdx.x * blockDim.x + threadIdx.x;
    if (idx >= EE) return;
    int s, d;
    if (idx < E) { s = ei[idx]; d = ei[E + idx]; } else { s = d = idx - E; }
    for (int h = 0; h < 4; ++h) {
        float v = lrelu(as1[s * 4 + h] + ad1[d * 4 + h]);
        atomicMax(&m1u[d * 4 + h], fenc(v));
    }
}

__global__ void dec_kernel(unsigned* p, int n) {
    int i = blockIdx.x * blockDim.x + threadIdx.x;
    if (i >= n) return;
    float f = fdec(p[i]);
    ((float*)p)[i] = f;
}

__global__ void den1_kernel(const int* __restrict__ ei, int E, int EE,
                            const float* __restrict__ as1, const float* __restrict__ ad1,
                            const float* __restrict__ m1f, float* __restrict__ den1) {
    int idx = blockIdx.x * blockDim.x + threadIdx.x;
    if (idx >= EE) return;
    int s, d;
    if (idx < E) { s = ei[idx]; d = ei[E + idx]; } else { s = d = idx - E; }
    for (int h = 0; h < 4; ++h) {
        float v = lrelu(as1[s * 4 + h] + ad1[d * 4 + h]);
        atomicAdd(&den1[d * 4 + h], expf(v - m1f[d * 4 + h]));
    }
}

__global__ void scatter1_kernel(const int* __restrict__ ei, int E, int EE,
                                const float* __restrict__ as1, const float* __restrict__ ad1,
                                const float* __restrict__ m1f, const float* __restrict__ den1,
                                const float* __restrict__ h1, float* __restrict__ out1) {
    size_t tid = (size_t)blockIdx.x * blockDim.x + threadIdx.x;
    int wid = (int)(tid >> 6);
    int lane = threadIdx.x & 63;
    if (wid >= EE) return;
    int s, d;
    if (wid < E) { s = ei[wid]; d = ei[E + wid]; } else { s = d = wid - E; }
    int h = lane >> 4;
    float v = lrelu(as1[s * 4 + h] + ad1[d * 4 + h]);
    float alpha = expf(v - m1f[d * 4 + h]) / den1[d * 4 + h];
    atomicAdd(&out1[(size_t)d * 64 + lane], alpha * h1[(size_t)s * 64 + lane]);
}

__global__ void elu1_kernel(float* __restrict__ out1, const float* __restrict__ b1, size_t n) {
    size_t i = (size_t)blockIdx.x * blockDim.x + threadIdx.x;
    if (i >= n) return;
    out1[i] = eluf(out1[i] + b1[i & 63]);
}

__global__ __launch_bounds__(256) void gemm2_kernel(
    const float* __restrict__ h2, const float* __restrict__ W2,
    const float* __restrict__ as_w, const float* __restrict__ ad_w,
    float* __restrict__ t2, float* __restrict__ as2, float* __restrict__ ad2, int N) {
    __shared__ float xs[8 * 64];
    int b0 = blockIdx.x * 8;
    for (int idx = threadIdx.x; idx < 8 * 64; idx += 256) {
        int node = b0 + (idx >> 6);
        xs[idx] = (node < N) ? h2[(size_t)node * 64 + (idx & 63)] : 0.f;
    }
    __syncthreads();
    int lane = threadIdx.x & 63;
    int w = threadIdx.x >> 6;
    int sub = lane >> 5, c = lane & 31;
    int li = w * 2 + sub;
    float acc = 0.f;
    for (int k = 0; k < 64; ++k) acc += xs[li * 64 + k] * W2[k * 32 + c];
    int n = b0 + li;
    if (n < N) {
        t2[(size_t)n * 32 + c] = acc;
        float vs = acc * as_w[c], vd = acc * ad_w[c];
        vs += __shfl_xor(vs, 1); vs += __shfl_xor(vs, 2); vs += __shfl_xor(vs, 4);
        vs += __shfl_xor(vs, 8); vs += __shfl_xor(vs, 16);
        vd += __shfl_xor(vd, 1); vd += __shfl_xor(vd, 2); vd += __shfl_xor(vd, 4);
        vd += __shfl_xor(vd, 8); vd += __shfl_xor(vd, 16);
        if (c == 0) { as2[n] = vs; ad2[n] = vd; }
    }
}

__global__ void max2_kernel(const int* __restrict__ ei, int E, int EE,
                            const float* __restrict__ as2, const float* __restrict__ ad2,
                            unsigned* __restrict__ m2u) {
    int idx = blockIdx.x * blockDim.x + threadIdx.x;
    if (idx >= EE) return;
    int s, d;
    if (idx < E) { s = ei[idx]; d = ei[E + idx]; } else { s = d = idx - E; }
    float v = lrelu(as2[s] + ad2[d]);
    atomicMax(&m2u[d], fenc(v));
}

__global__ void den2_kernel(const int* __restrict__ ei, int E, int EE,
                            const float* __restrict__ as2, const float* __restrict__ ad2,
                            const float* __restrict__ m2f, float* __restrict__ den2) {
    int idx = blockIdx.x * blockDim.x + threadIdx.x;
    if (idx >= EE) return;
    int s, d;
    if (idx < E) { s = ei[idx]; d = ei[E + idx]; } else { s = d = idx - E; }
    float v = lrelu(as2[s] + ad2[d]);
    atomicAdd(&den2[d], expf(v - m2f[d]));
}

__global__ void scatter2_kernel(const int* __restrict__ ei, int E, int EE,
                                const float* __restrict__ as2, const float* __restrict__ ad2,
                                const float* __restrict__ m2f, const float* __restrict__ den2,
                                const float* __restrict__ t2, float* __restrict__ out2) {
    size_t tid = (size_t)blockIdx.x * blockDim.x + threadIdx.x;
    int e = (int)(tid >> 5);
    if (e >= EE) return;
    int c = (int)(tid & 31);
    int s, d;
    if (e < E) { s = ei[e]; d = ei[E + e]; } else { s = d = e - E; }
    float v = lrelu(as2[s] + ad2[d]);
    float alpha = expf(v - m2f[d]) / den2[d];
    atomicAdd(&out2[(size_t)d * 32 + c], alpha * t2[(size_t)s * 32 + c]);
}

__global__ void pool_kernel(const float* __restrict__ out2, const float* __restrict__ b2,
                            const int* __restrict__ batch, float* __restrict__ pooled,
                            float* __restrict__ cnt, int N) {
    size_t i = (size_t)blockIdx.x * blockDim.x + threadIdx.x;
    if (i >= (size_t)N * 32) return;
    int n = (int)(i >> 5), c = (int)(i & 31);
    float v = eluf(out2[i] + b2[c]);
    int g = batch[n];
    atomicAdd(&pooled[g * 32 + c], v);
    if (c == 0) atomicAdd(&cnt[g], 1.f);
}

__global__ void final_kernel(const float* __restrict__ pooled, const float* __restrict__ cnt,
                             const float* __restrict__ fc_w, const float* __restrict__ fc_b,
                             float* __restrict__ out) {
    int g = threadIdx.x;
    if (g >= GV) return;
    float c = cnt[g];
    c = c > 1.f ? c : 1.f;
    float p[C2V];
    for (int j = 0; j < C2V; ++j) p[j] = pooled[g * C2V + j] / c;
    float l[NCLSV];
    float mx = -1e30f;
    for (int k = 0; k < NCLSV; ++k) {
        float acc = fc_b[k];
        for (int j = 0; j < C2V; ++j) acc += p[j] * fc_w[j * NCLSV + k];
        l[k] = acc;
        mx = fmaxf(mx, acc);
    }
    float s = 0.f;
    for (int k = 0; k < NCLSV; ++k) s += expf(l[k] - mx);
    float lse = mx + logf(s);
    for (int k = 0; k < NCLSV; ++k) out[g * NCLSV + k] = l[k] - lse;
}

extern "C" void kernel_launch(void* const* d_in, const int* in_sizes, int n_in,
                              void* d_out, int out_size, void* d_ws, size_t ws_size,
                              hipStream_t stream) {
    const float* x = (const float*)d_in[0];
    const int* ei = (const int*)d_in[1];
    const int* batch = (const int*)d_in[2];
    const float* W1 = (const float*)d_in[3];
    const float* att_src1 = (const float*)d_in[4];
    const float* att_dst1 = (const float*)d_in[5];
    const float* b1 = (const float*)d_in[6];
    const float* W2 = (const float*)d_in[7];
    const float* att_src2 = (const float*)d_in[8];
    const float* att_dst2 = (const float*)d_in[9];
    const float* b2 = (const float*)d_in[10];
    const float* fc_w = (const float*)d_in[11];
    const float* fc_b = (const float*)d_in[12];
    float* out = (float*)d_out;

    int N = in_sizes[0] / 256;
    int E = in_sizes[1] / 2;
    int EE = E + N;

    float* ws = (float*)d_ws;
    size_t off = 0;
    float* out1 = ws + off;                off += (size_t)64 * N;
    unsigned* m1u = (unsigned*)(ws + off); off += (size_t)4 * N;
    float* den1 = ws + off;                off += (size_t)4 * N;
    float* out2 = ws + off;                off += (size_t)32 * N;
    unsigned* m2u = (unsigned*)(ws + off); off += (size_t)N;
    float* den2 = ws + off;                off += (size_t)N;
    float* pooled = ws + off;              off += (size_t)GV * C2V;
    float* cnt = ws + off;                 off += (size_t)GV;
    size_t zTot = off;
    float* h1 = ws + off;                  off += (size_t)64 * N;
    float* as1 = ws + off;                 off += (size_t)4 * N;
    float* ad1 = ws + off;                 off += (size_t)4 * N;
    float* as2 = ws + off;                 off += (size_t)N;
    float* ad2 = ws + off;                 off += (size_t)N;
    float* t2 = h1;

    zero_kernel<<<2048, 256, 0, stream>>>(ws, zTot);

    gemm1_kernel<<<(N + 15) / 16, 256, 0, stream>>>(x, W1, att_src1, att_dst1, h1, as1, ad1, N);

    int egrid = (EE + 255) / 256;
    max1_kernel<<<egrid, 256, 0, stream>>>(ei, E, EE, as1, ad1, m1u);
    dec_kernel<<<(4 * N + 255) / 256, 256, 0, stream>>>(m1u, 4 * N);
    const float* m1f = (const float*)m1u;
    den1_kernel<<<egrid, 256, 0, stream>>>(ei, E, EE, as1, ad1, m1f, den1);
    scatter1_kernel<<<(int)(((size_t)EE * 64 + 255) / 256), 256, 0, stream>>>(
        ei, E, EE, as1, ad1, m1f, den1, h1, out1);

    elu1_kernel<<<(int)(((size_t)64 * N + 255) / 256), 256, 0, stream>>>(out1, b1, (size_t)64 * N);

    gemm2_kernel<<<(N + 7) / 8, 256, 0, stream>>>(out1, W2, att_src2, att_dst2, t2, as2, ad2, N);

    max2_kernel<<<egrid, 256, 0, stream>>>(ei, E, EE, as2, ad2, m2u);
    dec_kernel<<<(N + 255) / 256, 256, 0, stream>>>(m2u, N);
    const float* m2f = (const float*)m2u;
    den2_kernel<<<egrid, 256, 0, stream>>>(ei, E, EE, as2, ad2, m2f, den2);
    scatter2_kernel<<<(int)(((size_t)EE * 32 + 255) / 256), 256, 0, stream>>>(
        ei, E, EE, as2, ad2, m2f, den2, t2, out2);

    pool_kernel<<<(int)(((size_t)N * 32 + 255) / 256), 256, 0, stream>>>(out2, b2, batch, pooled, cnt, N);

    final_kernel<<<1, 64, 0, stream>>>(pooled, cnt, fc_w, fc_b, out);
}

// Round 2
// 794.039 us; speedup vs baseline: 2.1721x; 2.1721x over previous
//
#include <hip/hip_runtime.h>
#include <hip/hip_bf16.h>

#define GV 64
#define NCLSV 10
#define C2V 32

__device__ __forceinline__ float lrelu(float v) { return v > 0.f ? v : 0.2f * v; }
__device__ __forceinline__ float eluf(float v) { return v > 0.f ? v : expf(v) - 1.f; }

__global__ void zero_kernel(float* p, size_t n) {
    size_t i = (size_t)blockIdx.x * blockDim.x + threadIdx.x;
    size_t stride = (size_t)gridDim.x * blockDim.x;
    for (; i < n; i += stride) p[i] = 0.f;
}

// ---------- layer-1 GEMM + attention dots ----------
__global__ __launch_bounds__(256) void gemm1_kernel(
    const float* __restrict__ x, const float* __restrict__ W1,
    const float* __restrict__ as_w, const float* __restrict__ ad_w,
    float* __restrict__ h1, float* __restrict__ as1, float* __restrict__ ad1, int N) {
    __shared__ float xs[16 * 256];
    int b0 = blockIdx.x * 16;
    for (int idx = threadIdx.x; idx < 16 * 256; idx += 256) {
        int node = b0 + (idx >> 8);
        xs[idx] = (node < N) ? x[(size_t)node * 256 + (idx & 255)] : 0.f;
    }
    __syncthreads();
    int lane = threadIdx.x & 63;
    int w = threadIdx.x >> 6;
    float acc0 = 0.f, acc1 = 0.f, acc2 = 0.f, acc3 = 0.f;
    const float* xw = xs + w * 4 * 256;
    for (int k = 0; k < 256; ++k) {
        float wv = W1[k * 64 + lane];
        acc0 += xw[k] * wv;
        acc1 += xw[256 + k] * wv;
        acc2 += xw[512 + k] * wv;
        acc3 += xw[768 + k] * wv;
    }
    float asw = as_w[lane], adw = ad_w[lane];
    float accs[4] = {acc0, acc1, acc2, acc3};
    for (int i = 0; i < 4; ++i) {
        int n = b0 + w * 4 + i;
        if (n >= N) continue;
        float a = accs[i];
        h1[(size_t)n * 64 + lane] = a;
        float vs = a * asw, vd = a * adw;
        vs += __shfl_xor(vs, 1); vs += __shfl_xor(vs, 2);
        vs += __shfl_xor(vs, 4); vs += __shfl_xor(vs, 8);
        vd += __shfl_xor(vd, 1); vd += __shfl_xor(vd, 2);
        vd += __shfl_xor(vd, 4); vd += __shfl_xor(vd, 8);
        if ((lane & 15) == 0) {
            as1[n * 4 + (lane >> 4)] = vs;
            ad1[n * 4 + (lane >> 4)] = vd;
        }
    }
}

// ---------- CSR build ----------
__global__ void hist_kernel(const int* __restrict__ ei, int E, int EE, int* __restrict__ deg) {
    int idx = blockIdx.x * blockDim.x + threadIdx.x;
    int stride = gridDim.x * blockDim.x;
    for (; idx < EE; idx += stride) {
        int d = (idx < E) ? ei[E + idx] : idx - E;
        atomicAdd(&deg[d], 1);
    }
}

__global__ __launch_bounds__(1024) void blocksum_kernel(const int* __restrict__ deg,
                                                        int* __restrict__ partials, int N) {
    int i = blockIdx.x * 1024 + threadIdx.x;
    int v = (i < N) ? deg[i] : 0;
    for (int off = 32; off; off >>= 1) v += __shfl_down(v, off);
    __shared__ int ws[16];
    int w = threadIdx.x >> 6, lane = threadIdx.x & 63;
    if (lane == 0) ws[w] = v;
    __syncthreads();
    if (threadIdx.x == 0) {
        int s = 0;
        for (int k = 0; k < 16; ++k) s += ws[k];
        partials[blockIdx.x] = s;
    }
}

__global__ void scanpartials_kernel(const int* __restrict__ partials, int* __restrict__ blkoff,
                                    int nb, int* __restrict__ rowoff, int N, int EE) {
    int lane = threadIdx.x;  // 64 threads, nb <= 64
    int orig = (lane < nb) ? partials[lane] : 0;
    int v = orig;
    for (int off = 1; off < 64; off <<= 1) {
        int t = __shfl_up(v, off);
        if (lane >= off) v += t;
    }
    if (lane < nb) blkoff[lane] = v - orig;
    if (lane == 0) rowoff[N] = EE;
}

__global__ __launch_bounds__(1024) void scanblock_kernel(const int* __restrict__ deg,
                                                         const int* __restrict__ blkoff,
                                                         int* __restrict__ rowoff, int N) {
    int b = blockIdx.x;
    int i = b * 1024 + threadIdx.x;
    int orig = (i < N) ? deg[i] : 0;
    int v = orig;
    int lane = threadIdx.x & 63, w = threadIdx.x >> 6;
    for (int off = 1; off < 64; off <<= 1) {
        int t = __shfl_up(v, off);
        if (lane >= off) v += t;
    }
    __shared__ int ws[16];
    __shared__ int wsx[16];
    if (lane == 63) ws[w] = v;
    __syncthreads();
    if (threadIdx.x < 16) {
        int s = 0;
        for (int k = 0; k < threadIdx.x; ++k) s += ws[k];
        wsx[threadIdx.x] = s;
    }
    __syncthreads();
    if (i < N) rowoff[i] = blkoff[b] + wsx[w] + v - orig;
}

__global__ void fill_kernel(const int* __restrict__ ei, int E, int EE,
                            int* __restrict__ cursor, int* __restrict__ ssrc) {
    int idx = blockIdx.x * blockDim.x + threadIdx.x;
    int stride = gridDim.x * blockDim.x;
    for (; idx < EE; idx += stride) {
        int s, d;
        if (idx < E) { s = ei[idx]; d = ei[E + idx]; } else { s = d = idx - E; }
        int pos = atomicAdd(&cursor[d], 1);
        ssrc[pos] = s;
    }
}

// ---------- fused layer-1 edge pass: online softmax + weighted gather + bias + ELU ----------
__global__ __launch_bounds__(256) void gat1_kernel(
    const int* __restrict__ rowoff, const int* __restrict__ ssrc,
    const float* __restrict__ as1, const float* __restrict__ ad1,
    const float* __restrict__ h1, const float* __restrict__ b1,
    float* __restrict__ h2, int N) {
    int wid = (int)(((size_t)blockIdx.x * blockDim.x + threadIdx.x) >> 6);
    int lane = threadIdx.x & 63;
    if (wid >= N) return;
    int d = wid;
    int h = lane >> 4;
    int beg = rowoff[d], end = rowoff[d + 1];
    float adv = ad1[d * 4 + h];
    float m = -INFINITY, den = 0.f, acc = 0.f;
    int i = beg;
    for (; i + 2 <= end; i += 2) {
        int s0 = ssrc[i], s1 = ssrc[i + 1];
        float a0 = as1[s0 * 4 + h], a1 = as1[s1 * 4 + h];
        float hv0 = h1[(size_t)s0 * 64 + lane];
        float hv1 = h1[(size_t)s1 * 64 + lane];
        float e0 = lrelu(a0 + adv), e1 = lrelu(a1 + adv);
        float nm = fmaxf(m, fmaxf(e0, e1));
        float sc = __expf(m - nm);
        float w0 = __expf(e0 - nm), w1 = __expf(e1 - nm);
        den = den * sc + w0 + w1;
        acc = acc * sc + w0 * hv0 + w1 * hv1;
        m = nm;
    }
    if (i < end) {
        int s0 = ssrc[i];
        float hv0 = h1[(size_t)s0 * 64 + lane];
        float e0 = lrelu(as1[s0 * 4 + h] + adv);
        float nm = fmaxf(m, e0);
        float sc = __expf(m - nm), w0 = __expf(e0 - nm);
        den = den * sc + w0;
        acc = acc * sc + w0 * hv0;
    }
    h2[(size_t)d * 64 + lane] = eluf(acc / den + b1[lane]);
}

// ---------- layer-2 GEMM + attention dots ----------
__global__ __launch_bounds__(256) void gemm2_kernel(
    const float* __restrict__ h2, const float* __restrict__ W2,
    const float* __restrict__ as_w, const float* __restrict__ ad_w,
    float* __restrict__ t2, float* __restrict__ as2, float* __restrict__ ad2, int N) {
    __shared__ float xs[8 * 64];
    int b0 = blockIdx.x * 8;
    for (int idx = threadIdx.x; idx < 8 * 64; idx += 256) {
        int node = b0 + (idx >> 6);
        xs[idx] = (node < N) ? h2[(size_t)node * 64 + (idx & 63)] : 0.f;
    }
    __syncthreads();
    int lane = threadIdx.x & 63;
    int w = threadIdx.x >> 6;
    int sub = lane >> 5, c = lane & 31;
    int li = w * 2 + sub;
    float acc = 0.f;
    for (int k = 0; k < 64; ++k) acc += xs[li * 64 + k] * W2[k * 32 + c];
    int n = b0 + li;
    if (n < N) {
        t2[(size_t)n * 32 + c] = acc;
        float vs = acc * as_w[c], vd = acc * ad_w[c];
        vs += __shfl_xor(vs, 1); vs += __shfl_xor(vs, 2); vs += __shfl_xor(vs, 4);
        vs += __shfl_xor(vs, 8); vs += __shfl_xor(vs, 16);
        vd += __shfl_xor(vd, 1); vd += __shfl_xor(vd, 2); vd += __shfl_xor(vd, 4);
        vd += __shfl_xor(vd, 8); vd += __shfl_xor(vd, 16);
        if (c == 0) { as2[n] = vs; ad2[n] = vd; }
    }
}

// ---------- fused layer-2 edge pass + bias + ELU + mean-pool ----------
__global__ __launch_bounds__(256) void gat2_kernel(
    const int* __restrict__ rowoff, const int* __restrict__ ssrc,
    const float* __restrict__ as2, const float* __restrict__ ad2,
    const float* __restrict__ t2, const float* __restrict__ b2,
    const int* __restrict__ batch, float* __restrict__ pooled,
    float* __restrict__ cnt, int N) {
    int hw = (int)(((size_t)blockIdx.x * blockDim.x + threadIdx.x) >> 5);
    int c = threadIdx.x & 31;
    if (hw >= N) return;
    int d = hw;
    int beg = rowoff[d], end = rowoff[d + 1];
    float adv = ad2[d];
    float m = -INFINITY, den = 0.f, acc = 0.f;
    int i = beg;
    for (; i + 2 <= end; i += 2) {
        int s0 = ssrc[i], s1 = ssrc[i + 1];
        float a0 = as2[s0], a1 = as2[s1];
        float hv0 = t2[(size_t)s0 * 32 + c];
        float hv1 = t2[(size_t)s1 * 32 + c];
        float e0 = lrelu(a0 + adv), e1 = lrelu(a1 + adv);
        float nm = fmaxf(m, fmaxf(e0, e1));
        float sc = __expf(m - nm);
        float w0 = __expf(e0 - nm), w1 = __expf(e1 - nm);
        den = den * sc + w0 + w1;
        acc = acc * sc + w0 * hv0 + w1 * hv1;
        m = nm;
    }
    if (i < end) {
        int s0 = ssrc[i];
        float hv0 = t2[(size_t)s0 * 32 + c];
        float e0 = lrelu(as2[s0] + adv);
        float nm = fmaxf(m, e0);
        float sc = __expf(m - nm), w0 = __expf(e0 - nm);
        den = den * sc + w0;
        acc = acc * sc + w0 * hv0;
    }
    float v = eluf(acc / den + b2[c]);
    int g = batch[d];
    atomicAdd(&pooled[g * C2V + c], v);
    if (c == 0) atomicAdd(&cnt[g], 1.f);
}

__global__ void final_kernel(const float* __restrict__ pooled, const float* __restrict__ cnt,
                             const float* __restrict__ fc_w, const float* __restrict__ fc_b,
                             float* __restrict__ out) {
    int g = threadIdx.x;
    if (g >= GV) return;
    float c = cnt[g];
    c = c > 1.f ? c : 1.f;
    float p[C2V];
    for (int j = 0; j < C2V; ++j) p[j] = pooled[g * C2V + j] / c;
    float l[NCLSV];
    float mx = -1e30f;
    for (int k = 0; k < NCLSV; ++k) {
        float acc = fc_b[k];
        for (int j = 0; j < C2V; ++j) acc += p[j] * fc_w[j * NCLSV + k];
        l[k] = acc;
        mx = fmaxf(mx, acc);
    }
    float s = 0.f;
    for (int k = 0; k < NCLSV; ++k) s += expf(l[k] - mx);
    float lse = mx + logf(s);
    for (int k = 0; k < NCLSV; ++k) out[g * NCLSV + k] = l[k] - lse;
}

extern "C" void kernel_launch(void* const* d_in, const int* in_sizes, int n_in,
                              void* d_out, int out_size, void* d_ws, size_t ws_size,
                              hipStream_t stream) {
    const float* x = (const float*)d_in[0];
    const int* ei = (const int*)d_in[1];
    const int* batch = (const int*)d_in[2];
    const float* W1 = (const float*)d_in[3];
    const float* att_src1 = (const float*)d_in[4];
    const float* att_dst1 = (const float*)d_in[5];
    const float* b1 = (const float*)d_in[6];
    const float* W2 = (const float*)d_in[7];
    const float* att_src2 = (const float*)d_in[8];
    const float* att_dst2 = (const float*)d_in[9];
    const float* b2 = (const float*)d_in[10];
    const float* fc_w = (const float*)d_in[11];
    const float* fc_b = (const float*)d_in[12];
    float* out = (float*)d_out;

    int N = in_sizes[0] / 256;
    int E = in_sizes[1] / 2;
    int EE = E + N;
    int nb = (N + 1023) / 1024;

    float* ws = (float*)d_ws;
    size_t off = 0;
    int* deg = (int*)(ws + off);      off += (size_t)N;        // zeroed
    float* pooled = ws + off;         off += (size_t)GV * C2V; // zeroed
    float* cnt = ws + off;            off += (size_t)GV;       // zeroed
    size_t zTot = off;
    int* rowoff = (int*)(ws + off);   off += (size_t)N + 1;
    int* cursor = (int*)(ws + off);   off += (size_t)N;
    int* partials = (int*)(ws + off); off += 64;
    int* blkoff = (int*)(ws + off);   off += 64;
    int* ssrc = (int*)(ws + off);     off += (size_t)EE;
    float* h1 = ws + off;             off += (size_t)64 * N;   // reused as t2
    float* as1 = ws + off;            off += (size_t)4 * N;
    float* ad1 = ws + off;            off += (size_t)4 * N;
    float* h2 = ws + off;             off += (size_t)64 * N;
    float* as2 = ws + off;            off += (size_t)N;
    float* ad2 = ws + off;            off += (size_t)N;
    float* t2 = h1;

    // zero accumulators (replay-safe)
    zero_kernel<<<256, 256, 0, stream>>>(ws, zTot);

    // layer-1 linear + attention dots (independent of CSR build)
    gemm1_kernel<<<(N + 15) / 16, 256, 0, stream>>>(x, W1, att_src1, att_dst1, h1, as1, ad1, N);

    // CSR build (dst-sorted)
    hist_kernel<<<1024, 256, 0, stream>>>(ei, E, EE, deg);
    blocksum_kernel<<<nb, 1024, 0, stream>>>(deg, partials, N);
    scanpartials_kernel<<<1, 64, 0, stream>>>(partials, blkoff, nb, rowoff, N, EE);
    scanblock_kernel<<<nb, 1024, 0, stream>>>(deg, blkoff, rowoff, N);
    hipMemcpyAsync(cursor, rowoff, (size_t)N * sizeof(int), hipMemcpyDeviceToDevice, stream);
    fill_kernel<<<1024, 256, 0, stream>>>(ei, E, EE, cursor, ssrc);

    // fused layer-1 edge softmax + gather + bias + ELU
    gat1_kernel<<<(N + 3) / 4, 256, 0, stream>>>(rowoff, ssrc, as1, ad1, h1, b1, h2, N);

    // layer-2 linear + attention dots
    gemm2_kernel<<<(N + 7) / 8, 256, 0, stream>>>(h2, W2, att_src2, att_dst2, t2, as2, ad2, N);

    // fused layer-2 edge softmax + gather + bias + ELU + mean-pool
    gat2_kernel<<<(N + 7) / 8, 256, 0, stream>>>(rowoff, ssrc, as2, ad2, t2, b2, batch, pooled, cnt, N);

    // FC + log_softmax
    final_kernel<<<1, 64, 0, stream>>>(pooled, cnt, fc_w, fc_b, out);
}

// Round 3
// 424.725 us; speedup vs baseline: 4.0609x; 1.8695x over previous
//
#include <hip/hip_runtime.h>
#include <hip/hip_bf16.h>

#define GV 64
#define NCLSV 10
#define C2V 32

__device__ __forceinline__ float lrelu(float v) { return v > 0.f ? v : 0.2f * v; }
__device__ __forceinline__ float eluf(float v) { return v > 0.f ? v : expf(v) - 1.f; }

__global__ void zero_kernel(float* p, size_t n) {
    size_t i = (size_t)blockIdx.x * blockDim.x + threadIdx.x;
    size_t stride = (size_t)gridDim.x * blockDim.x;
    for (; i < n; i += stride) p[i] = 0.f;
}

// ---------- layer-1 GEMM + attention dots ----------
__global__ __launch_bounds__(256) void gemm1_kernel(
    const float* __restrict__ x, const float* __restrict__ W1,
    const float* __restrict__ as_w, const float* __restrict__ ad_w,
    float* __restrict__ h1, float* __restrict__ as1, float* __restrict__ ad1, int N) {
    __shared__ float xs[16 * 256];
    int b0 = blockIdx.x * 16;
    for (int idx = threadIdx.x; idx < 16 * 256; idx += 256) {
        int node = b0 + (idx >> 8);
        xs[idx] = (node < N) ? x[(size_t)node * 256 + (idx & 255)] : 0.f;
    }
    __syncthreads();
    int lane = threadIdx.x & 63;
    int w = threadIdx.x >> 6;
    float acc0 = 0.f, acc1 = 0.f, acc2 = 0.f, acc3 = 0.f;
    const float* xw = xs + w * 4 * 256;
    for (int k = 0; k < 256; ++k) {
        float wv = W1[k * 64 + lane];
        acc0 += xw[k] * wv;
        acc1 += xw[256 + k] * wv;
        acc2 += xw[512 + k] * wv;
        acc3 += xw[768 + k] * wv;
    }
    float asw = as_w[lane], adw = ad_w[lane];
    float accs[4] = {acc0, acc1, acc2, acc3};
    for (int i = 0; i < 4; ++i) {
        int n = b0 + w * 4 + i;
        if (n >= N) continue;
        float a = accs[i];
        h1[(size_t)n * 64 + lane] = a;
        float vs = a * asw, vd = a * adw;
        vs += __shfl_xor(vs, 1); vs += __shfl_xor(vs, 2);
        vs += __shfl_xor(vs, 4); vs += __shfl_xor(vs, 8);
        vd += __shfl_xor(vd, 1); vd += __shfl_xor(vd, 2);
        vd += __shfl_xor(vd, 4); vd += __shfl_xor(vd, 8);
        if ((lane & 15) == 0) {
            as1[n * 4 + (lane >> 4)] = vs;
            ad1[n * 4 + (lane >> 4)] = vd;
        }
    }
}

// ---------- CSR build ----------
__global__ void hist_kernel(const int* __restrict__ ei, int E, int EE, int* __restrict__ deg) {
    int idx = blockIdx.x * blockDim.x + threadIdx.x;
    int stride = gridDim.x * blockDim.x;
    for (; idx < EE; idx += stride) {
        int d = (idx < E) ? ei[E + idx] : idx - E;
        atomicAdd(&deg[d], 1);
    }
}

__global__ __launch_bounds__(1024) void blocksum_kernel(const int* __restrict__ deg,
                                                        int* __restrict__ partials, int N) {
    int i = blockIdx.x * 1024 + threadIdx.x;
    int v = (i < N) ? deg[i] : 0;
    for (int off = 32; off; off >>= 1) v += __shfl_down(v, off);
    __shared__ int ws[16];
    int w = threadIdx.x >> 6, lane = threadIdx.x & 63;
    if (lane == 0) ws[w] = v;
    __syncthreads();
    if (threadIdx.x == 0) {
        int s = 0;
        for (int k = 0; k < 16; ++k) s += ws[k];
        partials[blockIdx.x] = s;
    }
}

__global__ void scanpartials_kernel(const int* __restrict__ partials, int* __restrict__ blkoff,
                                    int nb, int* __restrict__ rowoff, int N, int EE) {
    int lane = threadIdx.x;  // 64 threads, nb <= 64
    int orig = (lane < nb) ? partials[lane] : 0;
    int v = orig;
    for (int off = 1; off < 64; off <<= 1) {
        int t = __shfl_up(v, off);
        if (lane >= off) v += t;
    }
    if (lane < nb) blkoff[lane] = v - orig;
    if (lane == 0) rowoff[N] = EE;
}

__global__ __launch_bounds__(1024) void scanblock_kernel(const int* __restrict__ deg,
                                                         const int* __restrict__ blkoff,
                                                         int* __restrict__ rowoff, int N) {
    int b = blockIdx.x;
    int i = b * 1024 + threadIdx.x;
    int orig = (i < N) ? deg[i] : 0;
    int v = orig;
    int lane = threadIdx.x & 63, w = threadIdx.x >> 6;
    for (int off = 1; off < 64; off <<= 1) {
        int t = __shfl_up(v, off);
        if (lane >= off) v += t;
    }
    __shared__ int ws[16];
    __shared__ int wsx[16];
    if (lane == 63) ws[w] = v;
    __syncthreads();
    if (threadIdx.x < 16) {
        int s = 0;
        for (int k = 0; k < threadIdx.x; ++k) s += ws[k];
        wsx[threadIdx.x] = s;
    }
    __syncthreads();
    if (i < N) rowoff[i] = blkoff[b] + wsx[w] + v - orig;
}

__global__ void fill_kernel(const int* __restrict__ ei, int E, int EE,
                            int* __restrict__ cursor, int* __restrict__ ssrc) {
    int idx = blockIdx.x * blockDim.x + threadIdx.x;
    int stride = gridDim.x * blockDim.x;
    for (; idx < EE; idx += stride) {
        int s, d;
        if (idx < E) { s = ei[idx]; d = ei[E + idx]; } else { s = d = idx - E; }
        int pos = atomicAdd(&cursor[d], 1);
        ssrc[pos] = s;
    }
}

// ---------- fused layer-1 edge pass: online softmax + weighted gather + bias + ELU ----------
__global__ __launch_bounds__(256) void gat1_kernel(
    const int* __restrict__ rowoff, const int* __restrict__ ssrc,
    const float* __restrict__ as1, const float* __restrict__ ad1,
    const float* __restrict__ h1, const float* __restrict__ b1,
    float* __restrict__ h2, int N) {
    int wid = (int)(((size_t)blockIdx.x * blockDim.x + threadIdx.x) >> 6);
    int lane = threadIdx.x & 63;
    if (wid >= N) return;
    int d = wid;
    int h = lane >> 4;
    int beg = rowoff[d], end = rowoff[d + 1];
    float adv = ad1[d * 4 + h];
    float m = -INFINITY, den = 0.f, acc = 0.f;
    int i = beg;
    for (; i + 4 <= end; i += 4) {
        int s0 = ssrc[i], s1 = ssrc[i + 1], s2 = ssrc[i + 2], s3 = ssrc[i + 3];
        float a0 = as1[s0 * 4 + h], a1 = as1[s1 * 4 + h];
        float a2 = as1[s2 * 4 + h], a3 = as1[s3 * 4 + h];
        float hv0 = h1[(size_t)s0 * 64 + lane];
        float hv1 = h1[(size_t)s1 * 64 + lane];
        float hv2 = h1[(size_t)s2 * 64 + lane];
        float hv3 = h1[(size_t)s3 * 64 + lane];
        float e0 = lrelu(a0 + adv), e1 = lrelu(a1 + adv);
        float e2 = lrelu(a2 + adv), e3 = lrelu(a3 + adv);
        float nm = fmaxf(fmaxf(fmaxf(m, e0), fmaxf(e1, e2)), e3);
        float sc = __expf(m - nm);
        float w0 = __expf(e0 - nm), w1 = __expf(e1 - nm);
        float w2 = __expf(e2 - nm), w3 = __expf(e3 - nm);
        den = den * sc + (w0 + w1) + (w2 + w3);
        acc = acc * sc + (w0 * hv0 + w1 * hv1) + (w2 * hv2 + w3 * hv3);
        m = nm;
    }
    for (; i < end; ++i) {
        int s0 = ssrc[i];
        float hv0 = h1[(size_t)s0 * 64 + lane];
        float e0 = lrelu(as1[s0 * 4 + h] + adv);
        float nm = fmaxf(m, e0);
        float sc = __expf(m - nm), w0 = __expf(e0 - nm);
        den = den * sc + w0;
        acc = acc * sc + w0 * hv0;
        m = nm;
    }
    h2[(size_t)d * 64 + lane] = eluf(acc / den + b1[lane]);
}

// ---------- layer-2 GEMM + attention dots ----------
__global__ __launch_bounds__(256) void gemm2_kernel(
    const float* __restrict__ h2, const float* __restrict__ W2,
    const float* __restrict__ as_w, const float* __restrict__ ad_w,
    float* __restrict__ t2, float* __restrict__ as2, float* __restrict__ ad2, int N) {
    __shared__ float xs[8 * 64];
    int b0 = blockIdx.x * 8;
    for (int idx = threadIdx.x; idx < 8 * 64; idx += 256) {
        int node = b0 + (idx >> 6);
        xs[idx] = (node < N) ? h2[(size_t)node * 64 + (idx & 63)] : 0.f;
    }
    __syncthreads();
    int lane = threadIdx.x & 63;
    int w = threadIdx.x >> 6;
    int sub = lane >> 5, c = lane & 31;
    int li = w * 2 + sub;
    float acc = 0.f;
    for (int k = 0; k < 64; ++k) acc += xs[li * 64 + k] * W2[k * 32 + c];
    int n = b0 + li;
    if (n < N) {
        t2[(size_t)n * 32 + c] = acc;
        float vs = acc * as_w[c], vd = acc * ad_w[c];
        vs += __shfl_xor(vs, 1); vs += __shfl_xor(vs, 2); vs += __shfl_xor(vs, 4);
        vs += __shfl_xor(vs, 8); vs += __shfl_xor(vs, 16);
        vd += __shfl_xor(vd, 1); vd += __shfl_xor(vd, 2); vd += __shfl_xor(vd, 4);
        vd += __shfl_xor(vd, 8); vd += __shfl_xor(vd, 16);
        if (c == 0) { as2[n] = vs; ad2[n] = vd; }
    }
}

// ---------- fused layer-2 edge pass + bias + ELU (no atomics) ----------
__global__ __launch_bounds__(256) void gat2_kernel(
    const int* __restrict__ rowoff, const int* __restrict__ ssrc,
    const float* __restrict__ as2, const float* __restrict__ ad2,
    const float* __restrict__ t2, const float* __restrict__ b2,
    float* __restrict__ h3, int N) {
    int hw = (int)(((size_t)blockIdx.x * blockDim.x + threadIdx.x) >> 5);
    int c = threadIdx.x & 31;
    if (hw >= N) return;
    int d = hw;
    int beg = rowoff[d], end = rowoff[d + 1];
    float adv = ad2[d];
    float m = -INFINITY, den = 0.f, acc = 0.f;
    int i = beg;
    for (; i + 4 <= end; i += 4) {
        int s0 = ssrc[i], s1 = ssrc[i + 1], s2 = ssrc[i + 2], s3 = ssrc[i + 3];
        float a0 = as2[s0], a1 = as2[s1], a2 = as2[s2], a3 = as2[s3];
        float hv0 = t2[(size_t)s0 * 32 + c];
        float hv1 = t2[(size_t)s1 * 32 + c];
        float hv2 = t2[(size_t)s2 * 32 + c];
        float hv3 = t2[(size_t)s3 * 32 + c];
        float e0 = lrelu(a0 + adv), e1 = lrelu(a1 + adv);
        float e2 = lrelu(a2 + adv), e3 = lrelu(a3 + adv);
        float nm = fmaxf(fmaxf(fmaxf(m, e0), fmaxf(e1, e2)), e3);
        float sc = __expf(m - nm);
        float w0 = __expf(e0 - nm), w1 = __expf(e1 - nm);
        float w2 = __expf(e2 - nm), w3 = __expf(e3 - nm);
        den = den * sc + (w0 + w1) + (w2 + w3);
        acc = acc * sc + (w0 * hv0 + w1 * hv1) + (w2 * hv2 + w3 * hv3);
        m = nm;
    }
    for (; i < end; ++i) {
        int s0 = ssrc[i];
        float hv0 = t2[(size_t)s0 * 32 + c];
        float e0 = lrelu(as2[s0] + adv);
        float nm = fmaxf(m, e0);
        float sc = __expf(m - nm), w0 = __expf(e0 - nm);
        den = den * sc + w0;
        acc = acc * sc + w0 * hv0;
        m = nm;
    }
    h3[(size_t)d * 32 + c] = eluf(acc / den + b2[c]);
}

// ---------- pooling: one block per graph, batch is sorted -> binary search bounds ----------
__device__ __forceinline__ int lowerb(const int* __restrict__ a, int n, int v) {
    int lo = 0, hi = n;
    while (lo < hi) {
        int mid = (lo + hi) >> 1;
        if (a[mid] < v) lo = mid + 1; else hi = mid;
    }
    return lo;
}

__global__ __launch_bounds__(256) void pool_kernel(
    const float* __restrict__ h3, const int* __restrict__ batch,
    float* __restrict__ pooled, float* __restrict__ cnt, int N) {
    int g = blockIdx.x;
    __shared__ int bounds[2];
    if (threadIdx.x == 0) bounds[0] = lowerb(batch, N, g);
    else if (threadIdx.x == 1) bounds[1] = lowerb(batch, N, g + 1);
    __syncthreads();
    int lo = bounds[0], hi = bounds[1];
    int c = threadIdx.x & 31;
    int grp = threadIdx.x >> 5;  // 8 groups
    float s = 0.f;
    for (int n = lo + grp; n < hi; n += 8) s += h3[(size_t)n * 32 + c];
    __shared__ float red[8][33];
    red[grp][c] = s;
    __syncthreads();
    if (grp == 0) {
        float t = 0.f;
        for (int k = 0; k < 8; ++k) t += red[k][c];
        pooled[g * C2V + c] = t;
        if (c == 0) cnt[g] = (float)(hi - lo);
    }
}

__global__ void final_kernel(const float* __restrict__ pooled, const float* __restrict__ cnt,
                             const float* __restrict__ fc_w, const float* __restrict__ fc_b,
                             float* __restrict__ out) {
    int g = threadIdx.x;
    if (g >= GV) return;
    float c = cnt[g];
    c = c > 1.f ? c : 1.f;
    float p[C2V];
    for (int j = 0; j < C2V; ++j) p[j] = pooled[g * C2V + j] / c;
    float l[NCLSV];
    float mx = -1e30f;
    for (int k = 0; k < NCLSV; ++k) {
        float acc = fc_b[k];
        for (int j = 0; j < C2V; ++j) acc += p[j] * fc_w[j * NCLSV + k];
        l[k] = acc;
        mx = fmaxf(mx, acc);
    }
    float s = 0.f;
    for (int k = 0; k < NCLSV; ++k) s += expf(l[k] - mx);
    float lse = mx + logf(s);
    for (int k = 0; k < NCLSV; ++k) out[g * NCLSV + k] = l[k] - lse;
}

extern "C" void kernel_launch(void* const* d_in, const int* in_sizes, int n_in,
                              void* d_out, int out_size, void* d_ws, size_t ws_size,
                              hipStream_t stream) {
    const float* x = (const float*)d_in[0];
    const int* ei = (const int*)d_in[1];
    const int* batch = (const int*)d_in[2];
    const float* W1 = (const float*)d_in[3];
    const float* att_src1 = (const float*)d_in[4];
    const float* att_dst1 = (const float*)d_in[5];
    const float* b1 = (const float*)d_in[6];
    const float* W2 = (const float*)d_in[7];
    const float* att_src2 = (const float*)d_in[8];
    const float* att_dst2 = (const float*)d_in[9];
    const float* b2 = (const float*)d_in[10];
    const float* fc_w = (const float*)d_in[11];
    const float* fc_b = (const float*)d_in[12];
    float* out = (float*)d_out;

    int N = in_sizes[0] / 256;
    int E = in_sizes[1] / 2;
    int EE = E + N;
    int nb = (N + 1023) / 1024;

    float* ws = (float*)d_ws;
    size_t off = 0;
    int* deg = (int*)(ws + off);      off += (size_t)N;        // zeroed each call
    size_t zTot = off;
    float* pooled = ws + off;         off += (size_t)GV * C2V;
    float* cnt = ws + off;            off += (size_t)GV;
    int* rowoff = (int*)(ws + off);   off += (size_t)N + 1;
    int* cursor = (int*)(ws + off);   off += (size_t)N;
    int* partials = (int*)(ws + off); off += 64;
    int* blkoff = (int*)(ws + off);   off += 64;
    int* ssrc = (int*)(ws + off);     off += (size_t)EE;
    float* h1 = ws + off;             off += (size_t)64 * N;   // reused as t2
    float* as1 = ws + off;            off += (size_t)4 * N;
    float* ad1 = ws + off;            off += (size_t)4 * N;
    float* h2 = ws + off;             off += (size_t)64 * N;   // reused as h3
    float* as2 = ws + off;            off += (size_t)N;
    float* ad2 = ws + off;            off += (size_t)N;
    float* t2 = h1;
    float* h3 = h2;

    // zero deg (replay-safe)
    zero_kernel<<<64, 256, 0, stream>>>(ws, zTot);

    // layer-1 linear + attention dots (independent of CSR build)
    gemm1_kernel<<<(N + 15) / 16, 256, 0, stream>>>(x, W1, att_src1, att_dst1, h1, as1, ad1, N);

    // CSR build (dst-sorted)
    hist_kernel<<<1024, 256, 0, stream>>>(ei, E, EE, deg);
    blocksum_kernel<<<nb, 1024, 0, stream>>>(deg, partials, N);
    scanpartials_kernel<<<1, 64, 0, stream>>>(partials, blkoff, nb, rowoff, N, EE);
    scanblock_kernel<<<nb, 1024, 0, stream>>>(deg, blkoff, rowoff, N);
    hipMemcpyAsync(cursor, rowoff, (size_t)N * sizeof(int), hipMemcpyDeviceToDevice, stream);
    fill_kernel<<<1024, 256, 0, stream>>>(ei, E, EE, cursor, ssrc);

    // fused layer-1 edge softmax + gather + bias + ELU
    gat1_kernel<<<(N + 3) / 4, 256, 0, stream>>>(rowoff, ssrc, as1, ad1, h1, b1, h2, N);

    // layer-2 linear + attention dots
    gemm2_kernel<<<(N + 7) / 8, 256, 0, stream>>>(h2, W2, att_src2, att_dst2, t2, as2, ad2, N);

    // fused layer-2 edge softmax + gather + bias + ELU (writes h3, no atomics)
    gat2_kernel<<<(N + 7) / 8, 256, 0, stream>>>(rowoff, ssrc, as2, ad2, t2, b2, h3, N);

    // pooling: one block per graph, no atomics
    pool_kernel<<<GV, 256, 0, stream>>>(h3, batch, pooled, cnt, N);

    // FC + log_softmax
    final_kernel<<<1, 64, 0, stream>>>(pooled, cnt, fc_w, fc_b, out);
}

// Round 4
// 356.940 us; speedup vs baseline: 4.8320x; 1.1899x over previous
//
#include <hip/hip_runtime.h>
#include <hip/hip_bf16.h>

#define GV 64
#define NCLSV 10
#define C2V 32

__device__ __forceinline__ float lrelu(float v) { return v > 0.f ? v : 0.2f * v; }
__device__ __forceinline__ float eluf(float v) { return v > 0.f ? v : expf(v) - 1.f; }

__global__ void zero_kernel(float* p, size_t n) {
    size_t i = (size_t)blockIdx.x * blockDim.x + threadIdx.x;
    size_t stride = (size_t)gridDim.x * blockDim.x;
    for (; i < n; i += stride) p[i] = 0.f;
}

// ---------- layer-1 GEMM + attention dots ----------
__global__ __launch_bounds__(256) void gemm1_kernel(
    const float* __restrict__ x, const float* __restrict__ W1,
    const float* __restrict__ as_w, const float* __restrict__ ad_w,
    float* __restrict__ h1, float* __restrict__ as1, float* __restrict__ ad1, int N) {
    __shared__ float xs[16 * 256];
    int b0 = blockIdx.x * 16;
    for (int idx = threadIdx.x; idx < 16 * 256; idx += 256) {
        int node = b0 + (idx >> 8);
        xs[idx] = (node < N) ? x[(size_t)node * 256 + (idx & 255)] : 0.f;
    }
    __syncthreads();
    int lane = threadIdx.x & 63;
    int w = threadIdx.x >> 6;
    float acc0 = 0.f, acc1 = 0.f, acc2 = 0.f, acc3 = 0.f;
    const float* xw = xs + w * 4 * 256;
    for (int k = 0; k < 256; ++k) {
        float wv = W1[k * 64 + lane];
        acc0 += xw[k] * wv;
        acc1 += xw[256 + k] * wv;
        acc2 += xw[512 + k] * wv;
        acc3 += xw[768 + k] * wv;
    }
    float asw = as_w[lane], adw = ad_w[lane];
    float accs[4] = {acc0, acc1, acc2, acc3};
    for (int i = 0; i < 4; ++i) {
        int n = b0 + w * 4 + i;
        if (n >= N) continue;
        float a = accs[i];
        h1[(size_t)n * 64 + lane] = a;
        float vs = a * asw, vd = a * adw;
        vs += __shfl_xor(vs, 1); vs += __shfl_xor(vs, 2);
        vs += __shfl_xor(vs, 4); vs += __shfl_xor(vs, 8);
        vd += __shfl_xor(vd, 1); vd += __shfl_xor(vd, 2);
        vd += __shfl_xor(vd, 4); vd += __shfl_xor(vd, 8);
        if ((lane & 15) == 0) {
            as1[n * 4 + (lane >> 4)] = vs;
            ad1[n * 4 + (lane >> 4)] = vd;
        }
    }
}

// ---------- CSR build: degree histogram + scan ----------
__global__ void hist_kernel(const int* __restrict__ ei, int E, int EE, int* __restrict__ deg) {
    int idx = blockIdx.x * blockDim.x + threadIdx.x;
    int stride = gridDim.x * blockDim.x;
    for (; idx < EE; idx += stride) {
        int d = (idx < E) ? ei[E + idx] : idx - E;
        atomicAdd(&deg[d], 1);
    }
}

__global__ __launch_bounds__(1024) void blocksum_kernel(const int* __restrict__ deg,
                                                        int* __restrict__ partials, int N) {
    int i = blockIdx.x * 1024 + threadIdx.x;
    int v = (i < N) ? deg[i] : 0;
    for (int off = 32; off; off >>= 1) v += __shfl_down(v, off);
    __shared__ int ws[16];
    int w = threadIdx.x >> 6, lane = threadIdx.x & 63;
    if (lane == 0) ws[w] = v;
    __syncthreads();
    if (threadIdx.x == 0) {
        int s = 0;
        for (int k = 0; k < 16; ++k) s += ws[k];
        partials[blockIdx.x] = s;
    }
}

__global__ void scanpartials_kernel(const int* __restrict__ partials, int* __restrict__ blkoff,
                                    int nb, int* __restrict__ rowoff, int N, int EE) {
    int lane = threadIdx.x;  // 64 threads, nb <= 64
    int orig = (lane < nb) ? partials[lane] : 0;
    int v = orig;
    for (int off = 1; off < 64; off <<= 1) {
        int t = __shfl_up(v, off);
        if (lane >= off) v += t;
    }
    if (lane < nb) blkoff[lane] = v - orig;
    if (lane == 0) rowoff[N] = EE;
}

__global__ __launch_bounds__(1024) void scanblock_kernel(const int* __restrict__ deg,
                                                         const int* __restrict__ blkoff,
                                                         int* __restrict__ rowoff, int N) {
    int b = blockIdx.x;
    int i = b * 1024 + threadIdx.x;
    int orig = (i < N) ? deg[i] : 0;
    int v = orig;
    int lane = threadIdx.x & 63, w = threadIdx.x >> 6;
    for (int off = 1; off < 64; off <<= 1) {
        int t = __shfl_up(v, off);
        if (lane >= off) v += t;
    }
    __shared__ int ws[16];
    __shared__ int wsx[16];
    if (lane == 63) ws[w] = v;
    __syncthreads();
    if (threadIdx.x < 16) {
        int s = 0;
        for (int k = 0; k < threadIdx.x; ++k) s += ws[k];
        wsx[threadIdx.x] = s;
    }
    __syncthreads();
    if (i < N) rowoff[i] = blkoff[b] + wsx[w] + v - orig;
}

// ---------- fill pass A: bucket edges by dst>>8 (196 buckets), per-block LDS hist ----------
__global__ __launch_bounds__(256) void bucketA_kernel(
    const int* __restrict__ ei, int E, int EE,
    const int* __restrict__ rowoff, int* __restrict__ gcur,
    int* __restrict__ bbuf, int N, int NB) {
    __shared__ int hist[256];
    __shared__ int base[256];
    __shared__ int cur[256];
    int span = (EE + gridDim.x - 1) / gridDim.x;
    int s0 = blockIdx.x * span;
    int s1 = min(s0 + span, EE);
    if (s0 >= s1) return;
    for (int t = threadIdx.x; t < 256; t += 256) { hist[t] = 0; cur[t] = 0; }
    __syncthreads();
    for (int i = s0 + threadIdx.x; i < s1; i += 256) {
        int d = (i < E) ? ei[E + i] : i - E;
        atomicAdd(&hist[d >> 8], 1);
    }
    __syncthreads();
    for (int t = threadIdx.x; t < NB; t += 256) {
        int c = hist[t];
        if (c) base[t] = rowoff[min(t << 8, N)] + atomicAdd(&gcur[t], c);
    }
    __syncthreads();
    for (int i = s0 + threadIdx.x; i < s1; i += 256) {
        int s, d;
        if (i < E) { s = ei[i]; d = ei[E + i]; } else { s = d = i - E; }
        int b = d >> 8;
        int lr = atomicAdd(&cur[b], 1);
        bbuf[base[b] + lr] = ((d & 255) << 24) | s;
    }
}

// ---------- fill pass B: within each bucket, place edges at exact CSR slots ----------
__global__ __launch_bounds__(256) void bucketB_kernel(
    const int* __restrict__ rowoff, const int* __restrict__ bbuf,
    int* __restrict__ ssrc, int N) {
    int k = blockIdx.x;
    __shared__ int cur[256];
    for (int t = threadIdx.x; t < 256; t += 256) cur[t] = 0;
    __syncthreads();
    int lo = rowoff[min(k << 8, N)];
    int hi = rowoff[min((k + 1) << 8, N)];
    int dbase = k << 8;
    for (int i = lo + threadIdx.x; i < hi; i += 256) {
        int v = bbuf[i];
        int dlow = (v >> 24) & 255;
        int s = v & 0xFFFFFF;
        int lr = atomicAdd(&cur[dlow], 1);
        ssrc[rowoff[dbase + dlow] + lr] = s;
    }
}

// ---------- fused layer-1 edge pass: online softmax + weighted gather + bias + ELU ----------
__global__ __launch_bounds__(256) void gat1_kernel(
    const int* __restrict__ rowoff, const int* __restrict__ ssrc,
    const float* __restrict__ as1, const float* __restrict__ ad1,
    const float* __restrict__ h1, const float* __restrict__ b1,
    float* __restrict__ h2, int N) {
    int wid = (int)(((size_t)blockIdx.x * blockDim.x + threadIdx.x) >> 6);
    int lane = threadIdx.x & 63;
    if (wid >= N) return;
    int d = wid;
    int h = lane >> 4;
    int beg = rowoff[d], end = rowoff[d + 1];
    float adv = ad1[d * 4 + h];
    float m = -INFINITY, den = 0.f, acc = 0.f;
    int i = beg;
    for (; i + 4 <= end; i += 4) {
        int s0 = ssrc[i], s1 = ssrc[i + 1], s2 = ssrc[i + 2], s3 = ssrc[i + 3];
        float a0 = as1[s0 * 4 + h], a1 = as1[s1 * 4 + h];
        float a2 = as1[s2 * 4 + h], a3 = as1[s3 * 4 + h];
        float hv0 = h1[(size_t)s0 * 64 + lane];
        float hv1 = h1[(size_t)s1 * 64 + lane];
        float hv2 = h1[(size_t)s2 * 64 + lane];
        float hv3 = h1[(size_t)s3 * 64 + lane];
        float e0 = lrelu(a0 + adv), e1 = lrelu(a1 + adv);
        float e2 = lrelu(a2 + adv), e3 = lrelu(a3 + adv);
        float nm = fmaxf(fmaxf(fmaxf(m, e0), fmaxf(e1, e2)), e3);
        float sc = __expf(m - nm);
        float w0 = __expf(e0 - nm), w1 = __expf(e1 - nm);
        float w2 = __expf(e2 - nm), w3 = __expf(e3 - nm);
        den = den * sc + (w0 + w1) + (w2 + w3);
        acc = acc * sc + (w0 * hv0 + w1 * hv1) + (w2 * hv2 + w3 * hv3);
        m = nm;
    }
    for (; i < end; ++i) {
        int s0 = ssrc[i];
        float hv0 = h1[(size_t)s0 * 64 + lane];
        float e0 = lrelu(as1[s0 * 4 + h] + adv);
        float nm = fmaxf(m, e0);
        float sc = __expf(m - nm), w0 = __expf(e0 - nm);
        den = den * sc + w0;
        acc = acc * sc + w0 * hv0;
        m = nm;
    }
    h2[(size_t)d * 64 + lane] = eluf(acc / den + b1[lane]);
}

// ---------- layer-2 GEMM + attention dots ----------
__global__ __launch_bounds__(256) void gemm2_kernel(
    const float* __restrict__ h2, const float* __restrict__ W2,
    const float* __restrict__ as_w, const float* __restrict__ ad_w,
    float* __restrict__ t2, float* __restrict__ as2, float* __restrict__ ad2, int N) {
    __shared__ float xs[8 * 64];
    int b0 = blockIdx.x * 8;
    for (int idx = threadIdx.x; idx < 8 * 64; idx += 256) {
        int node = b0 + (idx >> 6);
        xs[idx] = (node < N) ? h2[(size_t)node * 64 + (idx & 63)] : 0.f;
    }
    __syncthreads();
    int lane = threadIdx.x & 63;
    int w = threadIdx.x >> 6;
    int sub = lane >> 5, c = lane & 31;
    int li = w * 2 + sub;
    float acc = 0.f;
    for (int k = 0; k < 64; ++k) acc += xs[li * 64 + k] * W2[k * 32 + c];
    int n = b0 + li;
    if (n < N) {
        t2[(size_t)n * 32 + c] = acc;
        float vs = acc * as_w[c], vd = acc * ad_w[c];
        vs += __shfl_xor(vs, 1); vs += __shfl_xor(vs, 2); vs += __shfl_xor(vs, 4);
        vs += __shfl_xor(vs, 8); vs += __shfl_xor(vs, 16);
        vd += __shfl_xor(vd, 1); vd += __shfl_xor(vd, 2); vd += __shfl_xor(vd, 4);
        vd += __shfl_xor(vd, 8); vd += __shfl_xor(vd, 16);
        if (c == 0) { as2[n] = vs; ad2[n] = vd; }
    }
}

// ---------- fused layer-2 edge pass + bias + ELU (no atomics) ----------
__global__ __launch_bounds__(256) void gat2_kernel(
    const int* __restrict__ rowoff, const int* __restrict__ ssrc,
    const float* __restrict__ as2, const float* __restrict__ ad2,
    const float* __restrict__ t2, const float* __restrict__ b2,
    float* __restrict__ h3, int N) {
    int hw = (int)(((size_t)blockIdx.x * blockDim.x + threadIdx.x) >> 5);
    int c = threadIdx.x & 31;
    if (hw >= N) return;
    int d = hw;
    int beg = rowoff[d], end = rowoff[d + 1];
    float adv = ad2[d];
    float m = -INFINITY, den = 0.f, acc = 0.f;
    int i = beg;
    for (; i + 4 <= end; i += 4) {
        int s0 = ssrc[i], s1 = ssrc[i + 1], s2 = ssrc[i + 2], s3 = ssrc[i + 3];
        float a0 = as2[s0], a1 = as2[s1], a2 = as2[s2], a3 = as2[s3];
        float hv0 = t2[(size_t)s0 * 32 + c];
        float hv1 = t2[(size_t)s1 * 32 + c];
        float hv2 = t2[(size_t)s2 * 32 + c];
        float hv3 = t2[(size_t)s3 * 32 + c];
        float e0 = lrelu(a0 + adv), e1 = lrelu(a1 + adv);
        float e2 = lrelu(a2 + adv), e3 = lrelu(a3 + adv);
        float nm = fmaxf(fmaxf(fmaxf(m, e0), fmaxf(e1, e2)), e3);
        float sc = __expf(m - nm);
        float w0 = __expf(e0 - nm), w1 = __expf(e1 - nm);
        float w2 = __expf(e2 - nm), w3 = __expf(e3 - nm);
        den = den * sc + (w0 + w1) + (w2 + w3);
        acc = acc * sc + (w0 * hv0 + w1 * hv1) + (w2 * hv2 + w3 * hv3);
        m = nm;
    }
    for (; i < end; ++i) {
        int s0 = ssrc[i];
        float hv0 = t2[(size_t)s0 * 32 + c];
        float e0 = lrelu(as2[s0] + adv);
        float nm = fmaxf(m, e0);
        float sc = __expf(m - nm), w0 = __expf(e0 - nm);
        den = den * sc + w0;
        acc = acc * sc + w0 * hv0;
        m = nm;
    }
    h3[(size_t)d * 32 + c] = eluf(acc / den + b2[c]);
}

// ---------- pooling: one block per graph, batch sorted -> binary search bounds ----------
__device__ __forceinline__ int lowerb(const int* __restrict__ a, int n, int v) {
    int lo = 0, hi = n;
    while (lo < hi) {
        int mid = (lo + hi) >> 1;
        if (a[mid] < v) lo = mid + 1; else hi = mid;
    }
    return lo;
}

__global__ __launch_bounds__(256) void pool_kernel(
    const float* __restrict__ h3, const int* __restrict__ batch,
    float* __restrict__ pooled, float* __restrict__ cnt, int N) {
    int g = blockIdx.x;
    __shared__ int bounds[2];
    if (threadIdx.x == 0) bounds[0] = lowerb(batch, N, g);
    else if (threadIdx.x == 1) bounds[1] = lowerb(batch, N, g + 1);
    __syncthreads();
    int lo = bounds[0], hi = bounds[1];
    int c = threadIdx.x & 31;
    int grp = threadIdx.x >> 5;  // 8 groups
    float s = 0.f;
    for (int n = lo + grp; n < hi; n += 8) s += h3[(size_t)n * 32 + c];
    __shared__ float red[8][33];
    red[grp][c] = s;
    __syncthreads();
    if (grp == 0) {
        float t = 0.f;
        for (int k = 0; k < 8; ++k) t += red[k][c];
        pooled[g * C2V + c] = t;
        if (c == 0) cnt[g] = (float)(hi - lo);
    }
}

__global__ void final_kernel(const float* __restrict__ pooled, const float* __restrict__ cnt,
                             const float* __restrict__ fc_w, const float* __restrict__ fc_b,
                             float* __restrict__ out) {
    int g = threadIdx.x;
    if (g >= GV) return;
    float c = cnt[g];
    c = c > 1.f ? c : 1.f;
    float p[C2V];
    for (int j = 0; j < C2V; ++j) p[j] = pooled[g * C2V + j] / c;
    float l[NCLSV];
    float mx = -1e30f;
    for (int k = 0; k < NCLSV; ++k) {
        float acc = fc_b[k];
        for (int j = 0; j < C2V; ++j) acc += p[j] * fc_w[j * NCLSV + k];
        l[k] = acc;
        mx = fmaxf(mx, acc);
    }
    float s = 0.f;
    for (int k = 0; k < NCLSV; ++k) s += expf(l[k] - mx);
    float lse = mx + logf(s);
    for (int k = 0; k < NCLSV; ++k) out[g * NCLSV + k] = l[k] - lse;
}

extern "C" void kernel_launch(void* const* d_in, const int* in_sizes, int n_in,
                              void* d_out, int out_size, void* d_ws, size_t ws_size,
                              hipStream_t stream) {
    const float* x = (const float*)d_in[0];
    const int* ei = (const int*)d_in[1];
    const int* batch = (const int*)d_in[2];
    const float* W1 = (const float*)d_in[3];
    const float* att_src1 = (const float*)d_in[4];
    const float* att_dst1 = (const float*)d_in[5];
    const float* b1 = (const float*)d_in[6];
    const float* W2 = (const float*)d_in[7];
    const float* att_src2 = (const float*)d_in[8];
    const float* att_dst2 = (const float*)d_in[9];
    const float* b2 = (const float*)d_in[10];
    const float* fc_w = (const float*)d_in[11];
    const float* fc_b = (const float*)d_in[12];
    float* out = (float*)d_out;

    int N = in_sizes[0] / 256;
    int E = in_sizes[1] / 2;
    int EE = E + N;
    int nb = (N + 1023) / 1024;
    int NB = (N + 255) >> 8;  // buckets of 256 dst values

    float* ws = (float*)d_ws;
    size_t off = 0;
    int* deg = (int*)(ws + off);      off += (size_t)N;   // zeroed each call
    int* gcur = (int*)(ws + off);     off += 256;         // zeroed each call
    size_t zTot = off;
    float* pooled = ws + off;         off += (size_t)GV * C2V;
    float* cnt = ws + off;            off += (size_t)GV;
    int* rowoff = (int*)(ws + off);   off += (size_t)N + 1;
    int* partials = (int*)(ws + off); off += 64;
    int* blkoff = (int*)(ws + off);   off += 64;
    int* bbuf = (int*)(ws + off);     off += (size_t)EE;
    int* ssrc = (int*)(ws + off);     off += (size_t)EE;
    float* h1 = ws + off;             off += (size_t)64 * N;   // reused as t2
    float* as1 = ws + off;            off += (size_t)4 * N;
    float* ad1 = ws + off;            off += (size_t)4 * N;
    float* h2 = ws + off;             off += (size_t)64 * N;   // reused as h3
    float* as2 = ws + off;            off += (size_t)N;
    float* ad2 = ws + off;            off += (size_t)N;
    float* t2 = h1;
    float* h3 = h2;

    // zero deg + bucket cursors (replay-safe)
    zero_kernel<<<64, 256, 0, stream>>>(ws, zTot);

    // layer-1 linear + attention dots (independent of CSR build)
    gemm1_kernel<<<(N + 15) / 16, 256, 0, stream>>>(x, W1, att_src1, att_dst1, h1, as1, ad1, N);

    // CSR build (dst-sorted) via bucketed two-pass fill
    hist_kernel<<<1024, 256, 0, stream>>>(ei, E, EE, deg);
    blocksum_kernel<<<nb, 1024, 0, stream>>>(deg, partials, N);
    scanpartials_kernel<<<1, 64, 0, stream>>>(partials, blkoff, nb, rowoff, N, EE);
    scanblock_kernel<<<nb, 1024, 0, stream>>>(deg, blkoff, rowoff, N);
    bucketA_kernel<<<1024, 256, 0, stream>>>(ei, E, EE, rowoff, gcur, bbuf, N, NB);
    bucketB_kernel<<<NB, 256, 0, stream>>>(rowoff, bbuf, ssrc, N);

    // fused layer-1 edge softmax + gather + bias + ELU
    gat1_kernel<<<(N + 3) / 4, 256, 0, stream>>>(rowoff, ssrc, as1, ad1, h1, b1, h2, N);

    // layer-2 linear + attention dots
    gemm2_kernel<<<(N + 7) / 8, 256, 0, stream>>>(h2, W2, att_src2, att_dst2, t2, as2, ad2, N);

    // fused layer-2 edge softmax + gather + bias + ELU (writes h3, no atomics)
    gat2_kernel<<<(N + 7) / 8, 256, 0, stream>>>(rowoff, ssrc, as2, ad2, t2, b2, h3, N);

    // pooling: one block per graph, no atomics
    pool_kernel<<<GV, 256, 0, stream>>>(h3, batch, pooled, cnt, N);

    // FC + log_softmax
    final_kernel<<<1, 64, 0, stream>>>(pooled, cnt, fc_w, fc_b, out);
}

// Round 5
// 303.068 us; speedup vs baseline: 5.6909x; 1.1778x over previous
//
#include <hip/hip_runtime.h>
#include <hip/hip_bf16.h>

#define GV 64
#define NCLSV 10
#define C2V 32
#define CHUNK 256

__device__ __forceinline__ float lrelu(float v) { return v > 0.f ? v : 0.2f * v; }
__device__ __forceinline__ float eluf(float v) { return v > 0.f ? v : expf(v) - 1.f; }

__global__ void zero_kernel(int* p, int n) {
    int i = blockIdx.x * blockDim.x + threadIdx.x;
    if (i < n) p[i] = 0;
}

// ---------- layer-1 GEMM + attention dots ----------
__global__ __launch_bounds__(256) void gemm1_kernel(
    const float* __restrict__ x, const float* __restrict__ W1,
    const float* __restrict__ as_w, const float* __restrict__ ad_w,
    float* __restrict__ h1, float* __restrict__ as1, float* __restrict__ ad1, int N) {
    __shared__ float xs[16 * 256];
    int b0 = blockIdx.x * 16;
    for (int idx = threadIdx.x; idx < 16 * 256; idx += 256) {
        int node = b0 + (idx >> 8);
        xs[idx] = (node < N) ? x[(size_t)node * 256 + (idx & 255)] : 0.f;
    }
    __syncthreads();
    int lane = threadIdx.x & 63;
    int w = threadIdx.x >> 6;
    float acc0 = 0.f, acc1 = 0.f, acc2 = 0.f, acc3 = 0.f;
    const float* xw = xs + w * 4 * 256;
    for (int k = 0; k < 256; ++k) {
        float wv = W1[k * 64 + lane];
        acc0 += xw[k] * wv;
        acc1 += xw[256 + k] * wv;
        acc2 += xw[512 + k] * wv;
        acc3 += xw[768 + k] * wv;
    }
    float asw = as_w[lane], adw = ad_w[lane];
    float accs[4] = {acc0, acc1, acc2, acc3};
    for (int i = 0; i < 4; ++i) {
        int n = b0 + w * 4 + i;
        if (n >= N) continue;
        float a = accs[i];
        h1[(size_t)n * 64 + lane] = a;
        float vs = a * asw, vd = a * adw;
        vs += __shfl_xor(vs, 1); vs += __shfl_xor(vs, 2);
        vs += __shfl_xor(vs, 4); vs += __shfl_xor(vs, 8);
        vd += __shfl_xor(vd, 1); vd += __shfl_xor(vd, 2);
        vd += __shfl_xor(vd, 4); vd += __shfl_xor(vd, 8);
        if ((lane & 15) == 0) {
            as1[n * 4 + (lane >> 4)] = vs;
            ad1[n * 4 + (lane >> 4)] = vd;
        }
    }
}

// ---------- CSR build: bucket counts ----------
__global__ __launch_bounds__(256) void bucketPre_kernel(
    const int* __restrict__ ei, int E, int EE, int* __restrict__ bcnt) {
    __shared__ int hist[256];
    int span = (EE + gridDim.x - 1) / gridDim.x;
    int s0 = blockIdx.x * span;
    int s1 = min(s0 + span, EE);
    hist[threadIdx.x] = 0;
    __syncthreads();
    for (int i = s0 + threadIdx.x; i < s1; i += 256) {
        int d = (i < E) ? ei[E + i] : i - E;
        atomicAdd(&hist[d >> 8], 1);
    }
    __syncthreads();
    int c = hist[threadIdx.x];
    if (c) atomicAdd(&bcnt[threadIdx.x], c);
}

// ---------- scan 256 bucket counts (1 block) ----------
__global__ void bscan_kernel(const int* __restrict__ bcnt, int* __restrict__ bucketoff,
                             int* __restrict__ rowoff, int N, int EE) {
    __shared__ int wtot[4];
    int v = bcnt[threadIdx.x];
    int lane = threadIdx.x & 63, w = threadIdx.x >> 6;
    int inc = v;
    for (int o = 1; o < 64; o <<= 1) { int t = __shfl_up(inc, o); if (lane >= o) inc += t; }
    if (lane == 63) wtot[w] = inc;
    __syncthreads();
    int woff = 0;
    #pragma unroll
    for (int i = 0; i < 4; ++i) woff += (i < w) ? wtot[i] : 0;
    bucketoff[threadIdx.x + 1] = woff + inc;
    if (threadIdx.x == 0) { bucketoff[0] = 0; rowoff[N] = EE; }
}

// ---------- fill pass A: bucket edges by dst>>8 ----------
__global__ __launch_bounds__(256) void bucketA_kernel(
    const int* __restrict__ ei, int E, int EE,
    const int* __restrict__ bucketoff, int* __restrict__ gcur,
    int* __restrict__ bbuf) {
    __shared__ int hist[256];
    __shared__ int base[256];
    __shared__ int cur[256];
    int span = (EE + gridDim.x - 1) / gridDim.x;
    int s0 = blockIdx.x * span;
    int s1 = min(s0 + span, EE);
    if (s0 >= s1) return;
    hist[threadIdx.x] = 0; cur[threadIdx.x] = 0;
    __syncthreads();
    for (int i = s0 + threadIdx.x; i < s1; i += 256) {
        int d = (i < E) ? ei[E + i] : i - E;
        atomicAdd(&hist[d >> 8], 1);
    }
    __syncthreads();
    int c = hist[threadIdx.x];
    if (c) base[threadIdx.x] = bucketoff[threadIdx.x] + atomicAdd(&gcur[threadIdx.x], c);
    __syncthreads();
    for (int i = s0 + threadIdx.x; i < s1; i += 256) {
        int s, d;
        if (i < E) { s = ei[i]; d = ei[E + i]; } else { s = d = i - E; }
        int b = d >> 8;
        int lr = atomicAdd(&cur[b], 1);
        bbuf[base[b] + lr] = ((d & 255) << 24) | s;
    }
}

// ---------- fill pass B: per bucket, build rowoff + exact CSR placement ----------
__global__ __launch_bounds__(256) void bucketB_kernel(
    const int* __restrict__ bucketoff, const int* __restrict__ bbuf,
    int* __restrict__ rowoff, int* __restrict__ ssrc, int N) {
    int k = blockIdx.x;
    __shared__ int cnt[256];
    __shared__ int excl[256];
    __shared__ int cur[256];
    __shared__ int wtot[4];
    cnt[threadIdx.x] = 0; cur[threadIdx.x] = 0;
    __syncthreads();
    int lo = bucketoff[k], hi = bucketoff[k + 1];
    for (int i = lo + threadIdx.x; i < hi; i += 256)
        atomicAdd(&cnt[(bbuf[i] >> 24) & 255], 1);
    __syncthreads();
    int v = cnt[threadIdx.x];
    int lane = threadIdx.x & 63, w = threadIdx.x >> 6;
    int inc = v;
    for (int o = 1; o < 64; o <<= 1) { int t = __shfl_up(inc, o); if (lane >= o) inc += t; }
    if (lane == 63) wtot[w] = inc;
    __syncthreads();
    int woff = 0;
    #pragma unroll
    for (int i = 0; i < 4; ++i) woff += (i < w) ? wtot[i] : 0;
    int e = woff + inc - v;
    excl[threadIdx.x] = e;
    int dst = (k << 8) + threadIdx.x;
    if (dst < N) rowoff[dst] = lo + e;
    __syncthreads();
    for (int i = lo + threadIdx.x; i < hi; i += 256) {
        int pv = bbuf[i];
        int dlow = (pv >> 24) & 255;
        int lr = atomicAdd(&cur[dlow], 1);
        ssrc[lo + excl[dlow] + lr] = pv & 0xFFFFFF;
    }
}

// ---------- fused layer-1 edge pass: two-phase softmax + gather + bias + ELU ----------
__global__ __launch_bounds__(256) void gat1_kernel(
    const int* __restrict__ rowoff, const int* __restrict__ ssrc,
    const float* __restrict__ as1, const float* __restrict__ ad1,
    const float* __restrict__ h1, const float* __restrict__ b1,
    float* __restrict__ h2, int N) {
    __shared__ int s_s[4][CHUNK];
    __shared__ float s_w[4][4 * CHUNK];
    int wv = threadIdx.x >> 6;
    int lane = threadIdx.x & 63;
    int row = blockIdx.x * 4 + wv;
    if (row >= N) return;
    int beg = rowoff[row], end = rowoff[row + 1];
    int h = lane >> 4, j = lane & 15;
    int c = lane;
    float adv = ad1[row * 4 + h];
    float accum = 0.f, den = 0.f, m = -INFINITY;
    int* sb = s_s[wv];
    float* wb = s_w[wv];
    for (int cb = beg; cb < end; cb += CHUNK) {
        int clen = min(end - cb, CHUNK);
        // phase A: e per (edge, head), parallel over edges
        float mloc = -INFINITY;
        for (int t = j; t < clen; t += 16) {
            int s = ssrc[cb + t];
            if (h == 0) sb[t] = s;
            float e = lrelu(as1[s * 4 + h] + adv);
            wb[h * CHUNK + t] = e;
            mloc = fmaxf(mloc, e);
        }
        mloc = fmaxf(mloc, __shfl_xor(mloc, 1));
        mloc = fmaxf(mloc, __shfl_xor(mloc, 2));
        mloc = fmaxf(mloc, __shfl_xor(mloc, 4));
        mloc = fmaxf(mloc, __shfl_xor(mloc, 8));
        float dloc = 0.f;
        for (int t = j; t < clen; t += 16) {
            float e = wb[h * CHUNK + t];
            float wgt = __expf(e - mloc);
            wb[h * CHUNK + t] = wgt;
            dloc += wgt;
        }
        dloc += __shfl_xor(dloc, 1);
        dloc += __shfl_xor(dloc, 2);
        dloc += __shfl_xor(dloc, 4);
        dloc += __shfl_xor(dloc, 8);
        // phase B: lean weighted gather (lane = channel)
        const float* wch = wb + (c >> 4) * CHUNK;
        float cacc = 0.f;
        int t = 0;
        for (; t + 4 <= clen; t += 4) {
            int s0 = sb[t], s1 = sb[t + 1], s2 = sb[t + 2], s3 = sb[t + 3];
            float w0 = wch[t], w1 = wch[t + 1], w2 = wch[t + 2], w3 = wch[t + 3];
            float hv0 = h1[(size_t)s0 * 64 + c];
            float hv1 = h1[(size_t)s1 * 64 + c];
            float hv2 = h1[(size_t)s2 * 64 + c];
            float hv3 = h1[(size_t)s3 * 64 + c];
            cacc += (w0 * hv0 + w1 * hv1) + (w2 * hv2 + w3 * hv3);
        }
        for (; t < clen; ++t) {
            cacc += wch[t] * h1[(size_t)sb[t] * 64 + c];
        }
        // merge chunk into running state
        float nm = fmaxf(m, mloc);
        float so = __expf(m - nm), sn = __expf(mloc - nm);
        accum = accum * so + cacc * sn;
        den = den * so + dloc * sn;
        m = nm;
    }
    h2[(size_t)row * 64 + c] = eluf(accum / den + b1[c]);
}

// ---------- layer-2 GEMM + attention dots ----------
__global__ __launch_bounds__(256) void gemm2_kernel(
    const float* __restrict__ h2, const float* __restrict__ W2,
    const float* __restrict__ as_w, const float* __restrict__ ad_w,
    float* __restrict__ t2, float* __restrict__ as2, float* __restrict__ ad2, int N) {
    __shared__ float xs[8 * 64];
    int b0 = blockIdx.x * 8;
    for (int idx = threadIdx.x; idx < 8 * 64; idx += 256) {
        int node = b0 + (idx >> 6);
        xs[idx] = (node < N) ? h2[(size_t)node * 64 + (idx & 63)] : 0.f;
    }
    __syncthreads();
    int lane = threadIdx.x & 63;
    int w = threadIdx.x >> 6;
    int sub = lane >> 5, c = lane & 31;
    int li = w * 2 + sub;
    float acc = 0.f;
    for (int k = 0; k < 64; ++k) acc += xs[li * 64 + k] * W2[k * 32 + c];
    int n = b0 + li;
    if (n < N) {
        t2[(size_t)n * 32 + c] = acc;
        float vs = acc * as_w[c], vd = acc * ad_w[c];
        vs += __shfl_xor(vs, 1); vs += __shfl_xor(vs, 2); vs += __shfl_xor(vs, 4);
        vs += __shfl_xor(vs, 8); vs += __shfl_xor(vs, 16);
        vd += __shfl_xor(vd, 1); vd += __shfl_xor(vd, 2); vd += __shfl_xor(vd, 4);
        vd += __shfl_xor(vd, 8); vd += __shfl_xor(vd, 16);
        if (c == 0) { as2[n] = vs; ad2[n] = vd; }
    }
}

// ---------- fused layer-2 edge pass: two-phase softmax, 2 rows per wave ----------
__global__ __launch_bounds__(256) void gat2_kernel(
    const int* __restrict__ rowoff, const int* __restrict__ ssrc,
    const float* __restrict__ as2, const float* __restrict__ ad2,
    const float* __restrict__ t2, const float* __restrict__ b2,
    float* __restrict__ h3, int N) {
    __shared__ int s_s[8][CHUNK];
    __shared__ float s_w[8][CHUNK];
    int half = threadIdx.x >> 5;   // 8 half-waves per block
    int sl = threadIdx.x & 31;
    int row = blockIdx.x * 8 + half;
    if (row >= N) return;
    int beg = rowoff[row], end = rowoff[row + 1];
    float adv = ad2[row];
    float accum = 0.f, den = 0.f, m = -INFINITY;
    int* sb = s_s[half];
    float* wb = s_w[half];
    for (int cb = beg; cb < end; cb += CHUNK) {
        int clen = min(end - cb, CHUNK);
        float mloc = -INFINITY;
        for (int t = sl; t < clen; t += 32) {
            int s = ssrc[cb + t];
            sb[t] = s;
            float e = lrelu(as2[s] + adv);
            wb[t] = e;
            mloc = fmaxf(mloc, e);
        }
        mloc = fmaxf(mloc, __shfl_xor(mloc, 1));
        mloc = fmaxf(mloc, __shfl_xor(mloc, 2));
        mloc = fmaxf(mloc, __shfl_xor(mloc, 4));
        mloc = fmaxf(mloc, __shfl_xor(mloc, 8));
        mloc = fmaxf(mloc, __shfl_xor(mloc, 16));
        float dloc = 0.f;
        for (int t = sl; t < clen; t += 32) {
            float e = wb[t];
            float wgt = __expf(e - mloc);
            wb[t] = wgt;
            dloc += wgt;
        }
        dloc += __shfl_xor(dloc, 1);
        dloc += __shfl_xor(dloc, 2);
        dloc += __shfl_xor(dloc, 4);
        dloc += __shfl_xor(dloc, 8);
        dloc += __shfl_xor(dloc, 16);
        float cacc = 0.f;
        int t = 0;
        for (; t + 4 <= clen; t += 4) {
            int s0 = sb[t], s1 = sb[t + 1], s2 = sb[t + 2], s3 = sb[t + 3];
            float w0 = wb[t], w1 = wb[t + 1], w2 = wb[t + 2], w3 = wb[t + 3];
            float hv0 = t2[(size_t)s0 * 32 + sl];
            float hv1 = t2[(size_t)s1 * 32 + sl];
            float hv2 = t2[(size_t)s2 * 32 + sl];
            float hv3 = t2[(size_t)s3 * 32 + sl];
            cacc += (w0 * hv0 + w1 * hv1) + (w2 * hv2 + w3 * hv3);
        }
        for (; t < clen; ++t) {
            cacc += wb[t] * t2[(size_t)sb[t] * 32 + sl];
        }
        float nm = fmaxf(m, mloc);
        float so = __expf(m - nm), sn = __expf(mloc - nm);
        accum = accum * so + cacc * sn;
        den = den * so + dloc * sn;
        m = nm;
    }
    h3[(size_t)row * 32 + sl] = eluf(accum / den + b2[sl]);
}

// ---------- pooling: one block per graph ----------
__device__ __forceinline__ int lowerb(const int* __restrict__ a, int n, int v) {
    int lo = 0, hi = n;
    while (lo < hi) {
        int mid = (lo + hi) >> 1;
        if (a[mid] < v) lo = mid + 1; else hi = mid;
    }
    return lo;
}

__global__ __launch_bounds__(256) void pool_kernel(
    const float* __restrict__ h3, const int* __restrict__ batch,
    float* __restrict__ pooled, float* __restrict__ cnt, int N) {
    int g = blockIdx.x;
    __shared__ int bounds[2];
    if (threadIdx.x == 0) bounds[0] = lowerb(batch, N, g);
    else if (threadIdx.x == 1) bounds[1] = lowerb(batch, N, g + 1);
    __syncthreads();
    int lo = bounds[0], hi = bounds[1];
    int c = threadIdx.x & 31;
    int grp = threadIdx.x >> 5;
    float s = 0.f;
    for (int n = lo + grp; n < hi; n += 8) s += h3[(size_t)n * 32 + c];
    __shared__ float red[8][33];
    red[grp][c] = s;
    __syncthreads();
    if (grp == 0) {
        float t = 0.f;
        for (int k = 0; k < 8; ++k) t += red[k][c];
        pooled[g * C2V + c] = t;
        if (c == 0) cnt[g] = (float)(hi - lo);
    }
}

__global__ void final_kernel(const float* __restrict__ pooled, const float* __restrict__ cnt,
                             const float* __restrict__ fc_w, const float* __restrict__ fc_b,
                             float* __restrict__ out) {
    int g = threadIdx.x;
    if (g >= GV) return;
    float c = cnt[g];
    c = c > 1.f ? c : 1.f;
    float p[C2V];
    for (int j = 0; j < C2V; ++j) p[j] = pooled[g * C2V + j] / c;
    float l[NCLSV];
    float mx = -1e30f;
    for (int k = 0; k < NCLSV; ++k) {
        float acc = fc_b[k];
        for (int j = 0; j < C2V; ++j) acc += p[j] * fc_w[j * NCLSV + k];
        l[k] = acc;
        mx = fmaxf(mx, acc);
    }
    float s = 0.f;
    for (int k = 0; k < NCLSV; ++k) s += expf(l[k] - mx);
    float lse = mx + logf(s);
    for (int k = 0; k < NCLSV; ++k) out[g * NCLSV + k] = l[k] - lse;
}

extern "C" void kernel_launch(void* const* d_in, const int* in_sizes, int n_in,
                              void* d_out, int out_size, void* d_ws, size_t ws_size,
                              hipStream_t stream) {
    const float* x = (const float*)d_in[0];
    const int* ei = (const int*)d_in[1];
    const int* batch = (const int*)d_in[2];
    const float* W1 = (const float*)d_in[3];
    const float* att_src1 = (const float*)d_in[4];
    const float* att_dst1 = (const float*)d_in[5];
    const float* b1 = (const float*)d_in[6];
    const float* W2 = (const float*)d_in[7];
    const float* att_src2 = (const float*)d_in[8];
    const float* att_dst2 = (const float*)d_in[9];
    const float* b2 = (const float*)d_in[10];
    const float* fc_w = (const float*)d_in[11];
    const float* fc_b = (const float*)d_in[12];
    float* out = (float*)d_out;

    int N = in_sizes[0] / 256;
    int E = in_sizes[1] / 2;
    int EE = E + N;
    int NB = (N + 255) >> 8;

    float* ws = (float*)d_ws;
    size_t off = 0;
    int* gcur = (int*)(ws + off);      off += 256;   // zeroed each call
    int* bcnt = (int*)(ws + off);      off += 256;   // zeroed each call
    size_t zTot = off;
    int* bucketoff = (int*)(ws + off); off += 257;
    float* pooled = ws + off;          off += (size_t)GV * C2V;
    float* cnt = ws + off;             off += (size_t)GV;
    int* rowoff = (int*)(ws + off);    off += (size_t)N + 1;
    int* bbuf = (int*)(ws + off);      off += (size_t)EE;
    int* ssrc = (int*)(ws + off);      off += (size_t)EE;
    float* h1 = ws + off;              off += (size_t)64 * N;   // reused as t2
    float* as1 = ws + off;             off += (size_t)4 * N;
    float* ad1 = ws + off;             off += (size_t)4 * N;
    float* h2 = ws + off;              off += (size_t)64 * N;   // reused as h3
    float* as2 = ws + off;             off += (size_t)N;
    float* ad2 = ws + off;             off += (size_t)N;
    float* t2 = h1;
    float* h3 = h2;

    // zero bucket cursors/counts (replay-safe)
    zero_kernel<<<2, 256, 0, stream>>>((int*)ws, (int)zTot);

    // layer-1 linear + attention dots
    gemm1_kernel<<<(N + 15) / 16, 256, 0, stream>>>(x, W1, att_src1, att_dst1, h1, as1, ad1, N);

    // CSR build (dst-sorted), no far atomics on hot paths
    bucketPre_kernel<<<1024, 256, 0, stream>>>(ei, E, EE, bcnt);
    bscan_kernel<<<1, 256, 0, stream>>>(bcnt, bucketoff, rowoff, N, EE);
    bucketA_kernel<<<1024, 256, 0, stream>>>(ei, E, EE, bucketoff, gcur, bbuf);
    bucketB_kernel<<<NB, 256, 0, stream>>>(bucketoff, bbuf, rowoff, ssrc, N);

    // fused layer-1 edge softmax + gather + bias + ELU
    gat1_kernel<<<(N + 3) / 4, 256, 0, stream>>>(rowoff, ssrc, as1, ad1, h1, b1, h2, N);

    // layer-2 linear + attention dots
    gemm2_kernel<<<(N + 7) / 8, 256, 0, stream>>>(h2, W2, att_src2, att_dst2, t2, as2, ad2, N);

    // fused layer-2 edge softmax + gather + bias + ELU
    gat2_kernel<<<(N + 7) / 8, 256, 0, stream>>>(rowoff, ssrc, as2, ad2, t2, b2, h3, N);

    // pooling + FC + log_softmax
    pool_kernel<<<GV, 256, 0, stream>>>(h3, batch, pooled, cnt, N);
    final_kernel<<<1, 64, 0, stream>>>(pooled, cnt, fc_w, fc_b, out);
}

// Round 6
// 266.739 us; speedup vs baseline: 6.4660x; 1.1362x over previous
//
#include <hip/hip_runtime.h>
#include <hip/hip_bf16.h>

#define GV 64
#define NCLSV 10
#define C2V 32
#define CHUNK 256

__device__ __forceinline__ float lrelu(float v) { return v > 0.f ? v : 0.2f * v; }
__device__ __forceinline__ float eluf(float v) { return v > 0.f ? v : expf(v) - 1.f; }

__global__ void zero_kernel(int* p, int n) {
    int i = blockIdx.x * blockDim.x + threadIdx.x;
    if (i < n) p[i] = 0;
}

// ---------- layer-1 GEMM + attention dots; h1 stored bf16 ----------
__global__ __launch_bounds__(256) void gemm1_kernel(
    const float* __restrict__ x, const float* __restrict__ W1,
    const float* __restrict__ as_w, const float* __restrict__ ad_w,
    __hip_bfloat16* __restrict__ h1b, float* __restrict__ as1, float* __restrict__ ad1, int N) {
    __shared__ float xs[16 * 256];
    int b0 = blockIdx.x * 16;
    for (int idx = threadIdx.x; idx < 16 * 256; idx += 256) {
        int node = b0 + (idx >> 8);
        xs[idx] = (node < N) ? x[(size_t)node * 256 + (idx & 255)] : 0.f;
    }
    __syncthreads();
    int lane = threadIdx.x & 63;
    int w = threadIdx.x >> 6;
    float acc0 = 0.f, acc1 = 0.f, acc2 = 0.f, acc3 = 0.f;
    const float* xw = xs + w * 4 * 256;
    for (int k = 0; k < 256; ++k) {
        float wv = W1[k * 64 + lane];
        acc0 += xw[k] * wv;
        acc1 += xw[256 + k] * wv;
        acc2 += xw[512 + k] * wv;
        acc3 += xw[768 + k] * wv;
    }
    float asw = as_w[lane], adw = ad_w[lane];
    float accs[4] = {acc0, acc1, acc2, acc3};
    for (int i = 0; i < 4; ++i) {
        int n = b0 + w * 4 + i;
        if (n >= N) continue;
        float a = accs[i];
        h1b[(size_t)n * 64 + lane] = __float2bfloat16(a);
        float vs = a * asw, vd = a * adw;
        vs += __shfl_xor(vs, 1); vs += __shfl_xor(vs, 2);
        vs += __shfl_xor(vs, 4); vs += __shfl_xor(vs, 8);
        vd += __shfl_xor(vd, 1); vd += __shfl_xor(vd, 2);
        vd += __shfl_xor(vd, 4); vd += __shfl_xor(vd, 8);
        if ((lane & 15) == 0) {
            as1[n * 4 + (lane >> 4)] = vs;
            ad1[n * 4 + (lane >> 4)] = vd;
        }
    }
}

// ---------- CSR build: bucket counts ----------
__global__ __launch_bounds__(256) void bucketPre_kernel(
    const int* __restrict__ ei, int E, int EE, int* __restrict__ bcnt) {
    __shared__ int hist[256];
    int span = (EE + gridDim.x - 1) / gridDim.x;
    int s0 = blockIdx.x * span;
    int s1 = min(s0 + span, EE);
    hist[threadIdx.x] = 0;
    __syncthreads();
    for (int i = s0 + threadIdx.x; i < s1; i += 256) {
        int d = (i < E) ? ei[E + i] : i - E;
        atomicAdd(&hist[d >> 8], 1);
    }
    __syncthreads();
    int c = hist[threadIdx.x];
    if (c) atomicAdd(&bcnt[threadIdx.x], c);
}

__global__ void bscan_kernel(const int* __restrict__ bcnt, int* __restrict__ bucketoff,
                             int* __restrict__ rowoff, int N, int EE) {
    __shared__ int wtot[4];
    int v = bcnt[threadIdx.x];
    int lane = threadIdx.x & 63, w = threadIdx.x >> 6;
    int inc = v;
    for (int o = 1; o < 64; o <<= 1) { int t = __shfl_up(inc, o); if (lane >= o) inc += t; }
    if (lane == 63) wtot[w] = inc;
    __syncthreads();
    int woff = 0;
    #pragma unroll
    for (int i = 0; i < 4; ++i) woff += (i < w) ? wtot[i] : 0;
    bucketoff[threadIdx.x + 1] = woff + inc;
    if (threadIdx.x == 0) { bucketoff[0] = 0; rowoff[N] = EE; }
}

__global__ __launch_bounds__(256) void bucketA_kernel(
    const int* __restrict__ ei, int E, int EE,
    const int* __restrict__ bucketoff, int* __restrict__ gcur,
    int* __restrict__ bbuf) {
    __shared__ int hist[256];
    __shared__ int base[256];
    __shared__ int cur[256];
    int span = (EE + gridDim.x - 1) / gridDim.x;
    int s0 = blockIdx.x * span;
    int s1 = min(s0 + span, EE);
    if (s0 >= s1) return;
    hist[threadIdx.x] = 0; cur[threadIdx.x] = 0;
    __syncthreads();
    for (int i = s0 + threadIdx.x; i < s1; i += 256) {
        int d = (i < E) ? ei[E + i] : i - E;
        atomicAdd(&hist[d >> 8], 1);
    }
    __syncthreads();
    int c = hist[threadIdx.x];
    if (c) base[threadIdx.x] = bucketoff[threadIdx.x] + atomicAdd(&gcur[threadIdx.x], c);
    __syncthreads();
    for (int i = s0 + threadIdx.x; i < s1; i += 256) {
        int s, d;
        if (i < E) { s = ei[i]; d = ei[E + i]; } else { s = d = i - E; }
        int b = d >> 8;
        int lr = atomicAdd(&cur[b], 1);
        bbuf[base[b] + lr] = ((d & 255) << 24) | s;
    }
}

__global__ __launch_bounds__(256) void bucketB_kernel(
    const int* __restrict__ bucketoff, const int* __restrict__ bbuf,
    int* __restrict__ rowoff, int* __restrict__ ssrc, int N) {
    int k = blockIdx.x;
    __shared__ int cnt[256];
    __shared__ int excl[256];
    __shared__ int cur[256];
    __shared__ int wtot[4];
    cnt[threadIdx.x] = 0; cur[threadIdx.x] = 0;
    __syncthreads();
    int lo = bucketoff[k], hi = bucketoff[k + 1];
    for (int i = lo + threadIdx.x; i < hi; i += 256)
        atomicAdd(&cnt[(bbuf[i] >> 24) & 255], 1);
    __syncthreads();
    int v = cnt[threadIdx.x];
    int lane = threadIdx.x & 63, w = threadIdx.x >> 6;
    int inc = v;
    for (int o = 1; o < 64; o <<= 1) { int t = __shfl_up(inc, o); if (lane >= o) inc += t; }
    if (lane == 63) wtot[w] = inc;
    __syncthreads();
    int woff = 0;
    #pragma unroll
    for (int i = 0; i < 4; ++i) woff += (i < w) ? wtot[i] : 0;
    int e = woff + inc - v;
    excl[threadIdx.x] = e;
    int dst = (k << 8) + threadIdx.x;
    if (dst < N) rowoff[dst] = lo + e;
    __syncthreads();
    for (int i = lo + threadIdx.x; i < hi; i += 256) {
        int pv = bbuf[i];
        int dlow = (pv >> 24) & 255;
        int lr = atomicAdd(&cur[dlow], 1);
        ssrc[lo + excl[dlow] + lr] = pv & 0xFFFFFF;
    }
}

// ---------- fused layer-1 edge pass: two-phase softmax + bf16 gather, 2-way edge parity ----------
__global__ __launch_bounds__(256) void gat1_kernel(
    const int* __restrict__ rowoff, const int* __restrict__ ssrc,
    const float* __restrict__ as1, const float* __restrict__ ad1,
    const __hip_bfloat16* __restrict__ h1b, const float* __restrict__ b1,
    float* __restrict__ h2, int N) {
    __shared__ int s_s[4][CHUNK];
    __shared__ float s_w[4][4 * CHUNK];   // layout [t*4 + h]
    int wv = threadIdx.x >> 6;
    int lane = threadIdx.x & 63;
    int row = blockIdx.x * 4 + wv;
    if (row >= N) return;
    int beg = rowoff[row], end = rowoff[row + 1];
    int h = lane >> 4, j = lane & 15;     // phase A roles
    int par = lane >> 5, cp = lane & 31;  // phase B roles: channels 2cp,2cp+1
    int headB = cp >> 3;
    float adv = ad1[row * 4 + h];
    float accx = 0.f, accy = 0.f, den = 0.f, m = -INFINITY;
    int* sb = s_s[wv];
    float* wb = s_w[wv];
    for (int cb = beg; cb < end; cb += CHUNK) {
        int clen = min(end - cb, CHUNK);
        // phase A: score per (edge, head), edge-parallel
        float mloc = -INFINITY;
        for (int t = j; t < clen; t += 16) {
            int s = ssrc[cb + t];
            if (h == 0) sb[t] = s;
            float e = lrelu(as1[s * 4 + h] + adv);
            wb[t * 4 + h] = e;
            mloc = fmaxf(mloc, e);
        }
        mloc = fmaxf(mloc, __shfl_xor(mloc, 1));
        mloc = fmaxf(mloc, __shfl_xor(mloc, 2));
        mloc = fmaxf(mloc, __shfl_xor(mloc, 4));
        mloc = fmaxf(mloc, __shfl_xor(mloc, 8));
        float dloc = 0.f;
        for (int t = j; t < clen; t += 16) {
            float e = wb[t * 4 + h];
            float wgt = __expf(e - mloc);
            wb[t * 4 + h] = wgt;
            dloc += wgt;
        }
        dloc += __shfl_xor(dloc, 1);
        dloc += __shfl_xor(dloc, 2);
        dloc += __shfl_xor(dloc, 4);
        dloc += __shfl_xor(dloc, 8);
        // phase B: bf16x2 gather, 2-way edge parity, 4-edge unroll per parity
        float cx = 0.f, cy = 0.f;
        int t = par;
        for (; t + 6 < clen; t += 8) {
            int s0 = sb[t], s1 = sb[t + 2], s2 = sb[t + 4], s3 = sb[t + 6];
            float w0 = wb[t * 4 + headB], w1 = wb[(t + 2) * 4 + headB];
            float w2 = wb[(t + 4) * 4 + headB], w3 = wb[(t + 6) * 4 + headB];
            __hip_bfloat162 p0 = *(const __hip_bfloat162*)&h1b[(size_t)s0 * 64 + 2 * cp];
            __hip_bfloat162 p1 = *(const __hip_bfloat162*)&h1b[(size_t)s1 * 64 + 2 * cp];
            __hip_bfloat162 p2 = *(const __hip_bfloat162*)&h1b[(size_t)s2 * 64 + 2 * cp];
            __hip_bfloat162 p3 = *(const __hip_bfloat162*)&h1b[(size_t)s3 * 64 + 2 * cp];
            cx += w0 * __bfloat162float(p0.x) + w1 * __bfloat162float(p1.x)
                + w2 * __bfloat162float(p2.x) + w3 * __bfloat162float(p3.x);
            cy += w0 * __bfloat162float(p0.y) + w1 * __bfloat162float(p1.y)
                + w2 * __bfloat162float(p2.y) + w3 * __bfloat162float(p3.y);
        }
        for (; t < clen; t += 2) {
            int s0 = sb[t];
            float w0 = wb[t * 4 + headB];
            __hip_bfloat162 p0 = *(const __hip_bfloat162*)&h1b[(size_t)s0 * 64 + 2 * cp];
            cx += w0 * __bfloat162float(p0.x);
            cy += w0 * __bfloat162float(p0.y);
        }
        // merge chunk into running state
        float nm = fmaxf(m, mloc);
        float so = __expf(m - nm), sn = __expf(mloc - nm);
        accx = accx * so + cx * sn;
        accy = accy * so + cy * sn;
        den = den * so + dloc * sn;
        m = nm;
    }
    // fold edge parity
    accx += __shfl_xor(accx, 32);
    accy += __shfl_xor(accy, 32);
    if (par == 0) {
        float2 o;
        o.x = eluf(accx / den + b1[2 * cp]);
        o.y = eluf(accy / den + b1[2 * cp + 1]);
        *(float2*)&h2[(size_t)row * 64 + 2 * cp] = o;
    }
}

// ---------- layer-2 GEMM + attention dots; t2 stored bf16 ----------
__global__ __launch_bounds__(256) void gemm2_kernel(
    const float* __restrict__ h2, const float* __restrict__ W2,
    const float* __restrict__ as_w, const float* __restrict__ ad_w,
    __hip_bfloat16* __restrict__ t2b, float* __restrict__ as2, float* __restrict__ ad2, int N) {
    __shared__ float xs[8 * 64];
    int b0 = blockIdx.x * 8;
    for (int idx = threadIdx.x; idx < 8 * 64; idx += 256) {
        int node = b0 + (idx >> 6);
        xs[idx] = (node < N) ? h2[(size_t)node * 64 + (idx & 63)] : 0.f;
    }
    __syncthreads();
    int lane = threadIdx.x & 63;
    int w = threadIdx.x >> 6;
    int sub = lane >> 5, c = lane & 31;
    int li = w * 2 + sub;
    float acc = 0.f;
    for (int k = 0; k < 64; ++k) acc += xs[li * 64 + k] * W2[k * 32 + c];
    int n = b0 + li;
    if (n < N) {
        t2b[(size_t)n * 32 + c] = __float2bfloat16(acc);
        float vs = acc * as_w[c], vd = acc * ad_w[c];
        vs += __shfl_xor(vs, 1); vs += __shfl_xor(vs, 2); vs += __shfl_xor(vs, 4);
        vs += __shfl_xor(vs, 8); vs += __shfl_xor(vs, 16);
        vd += __shfl_xor(vd, 1); vd += __shfl_xor(vd, 2); vd += __shfl_xor(vd, 4);
        vd += __shfl_xor(vd, 8); vd += __shfl_xor(vd, 16);
        if (c == 0) { as2[n] = vs; ad2[n] = vd; }
    }
}

// ---------- fused layer-2 edge pass: wave per row, 4-way edge parity, bf16 gather ----------
__global__ __launch_bounds__(256) void gat2_kernel(
    const int* __restrict__ rowoff, const int* __restrict__ ssrc,
    const float* __restrict__ as2, const float* __restrict__ ad2,
    const __hip_bfloat16* __restrict__ t2b, const float* __restrict__ b2,
    float* __restrict__ h3, int N) {
    __shared__ int s_s[4][CHUNK];
    __shared__ float s_w[4][CHUNK];
    int wv = threadIdx.x >> 6;
    int lane = threadIdx.x & 63;
    int row = blockIdx.x * 4 + wv;
    if (row >= N) return;
    int beg = rowoff[row], end = rowoff[row + 1];
    int par = lane >> 4, cp = lane & 15;  // channels 2cp,2cp+1
    float adv = ad2[row];
    float accx = 0.f, accy = 0.f, den = 0.f, m = -INFINITY;
    int* sb = s_s[wv];
    float* wb = s_w[wv];
    for (int cb = beg; cb < end; cb += CHUNK) {
        int clen = min(end - cb, CHUNK);
        // phase A: all 64 lanes edge-parallel
        float mloc = -INFINITY;
        for (int t = lane; t < clen; t += 64) {
            int s = ssrc[cb + t];
            sb[t] = s;
            float e = lrelu(as2[s] + adv);
            wb[t] = e;
            mloc = fmaxf(mloc, e);
        }
        mloc = fmaxf(mloc, __shfl_xor(mloc, 1));
        mloc = fmaxf(mloc, __shfl_xor(mloc, 2));
        mloc = fmaxf(mloc, __shfl_xor(mloc, 4));
        mloc = fmaxf(mloc, __shfl_xor(mloc, 8));
        mloc = fmaxf(mloc, __shfl_xor(mloc, 16));
        mloc = fmaxf(mloc, __shfl_xor(mloc, 32));
        float dloc = 0.f;
        for (int t = lane; t < clen; t += 64) {
            float wgt = __expf(wb[t] - mloc);
            wb[t] = wgt;
            dloc += wgt;
        }
        dloc += __shfl_xor(dloc, 1);
        dloc += __shfl_xor(dloc, 2);
        dloc += __shfl_xor(dloc, 4);
        dloc += __shfl_xor(dloc, 8);
        dloc += __shfl_xor(dloc, 16);
        dloc += __shfl_xor(dloc, 32);
        // phase B: 4-way parity, 2-edge unroll (8 edges in flight per wave)
        float cx = 0.f, cy = 0.f;
        int t = par;
        for (; t + 4 < clen; t += 8) {
            int s0 = sb[t], s1 = sb[t + 4];
            float w0 = wb[t], w1 = wb[t + 4];
            __hip_bfloat162 p0 = *(const __hip_bfloat162*)&t2b[(size_t)s0 * 32 + 2 * cp];
            __hip_bfloat162 p1 = *(const __hip_bfloat162*)&t2b[(size_t)s1 * 32 + 2 * cp];
            cx += w0 * __bfloat162float(p0.x) + w1 * __bfloat162float(p1.x);
            cy += w0 * __bfloat162float(p0.y) + w1 * __bfloat162float(p1.y);
        }
        for (; t < clen; t += 4) {
            int s0 = sb[t];
            float w0 = wb[t];
            __hip_bfloat162 p0 = *(const __hip_bfloat162*)&t2b[(size_t)s0 * 32 + 2 * cp];
            cx += w0 * __bfloat162float(p0.x);
            cy += w0 * __bfloat162float(p0.y);
        }
        float nm = fmaxf(m, mloc);
        float so = __expf(m - nm), sn = __expf(mloc - nm);
        accx = accx * so + cx * sn;
        accy = accy * so + cy * sn;
        den = den * so + dloc * sn;
        m = nm;
    }
    accx += __shfl_xor(accx, 16);
    accx += __shfl_xor(accx, 32);
    accy += __shfl_xor(accy, 16);
    accy += __shfl_xor(accy, 32);
    if (par == 0) {
        float2 o;
        o.x = eluf(accx / den + b2[2 * cp]);
        o.y = eluf(accy / den + b2[2 * cp + 1]);
        *(float2*)&h3[(size_t)row * 32 + 2 * cp] = o;
    }
}

// ---------- pooling: one block per graph ----------
__device__ __forceinline__ int lowerb(const int* __restrict__ a, int n, int v) {
    int lo = 0, hi = n;
    while (lo < hi) {
        int mid = (lo + hi) >> 1;
        if (a[mid] < v) lo = mid + 1; else hi = mid;
    }
    return lo;
}

__global__ __launch_bounds__(256) void pool_kernel(
    const float* __restrict__ h3, const int* __restrict__ batch,
    float* __restrict__ pooled, float* __restrict__ cnt, int N) {
    int g = blockIdx.x;
    __shared__ int bounds[2];
    if (threadIdx.x == 0) bounds[0] = lowerb(batch, N, g);
    else if (threadIdx.x == 1) bounds[1] = lowerb(batch, N, g + 1);
    __syncthreads();
    int lo = bounds[0], hi = bounds[1];
    int c = threadIdx.x & 31;
    int grp = threadIdx.x >> 5;
    float s = 0.f;
    for (int n = lo + grp; n < hi; n += 8) s += h3[(size_t)n * 32 + c];
    __shared__ float red[8][33];
    red[grp][c] = s;
    __syncthreads();
    if (grp == 0) {
        float t = 0.f;
        for (int k = 0; k < 8; ++k) t += red[k][c];
        pooled[g * C2V + c] = t;
        if (c == 0) cnt[g] = (float)(hi - lo);
    }
}

__global__ void final_kernel(const float* __restrict__ pooled, const float* __restrict__ cnt,
                             const float* __restrict__ fc_w, const float* __restrict__ fc_b,
                             float* __restrict__ out) {
    int g = threadIdx.x;
    if (g >= GV) return;
    float c = cnt[g];
    c = c > 1.f ? c : 1.f;
    float p[C2V];
    for (int j = 0; j < C2V; ++j) p[j] = pooled[g * C2V + j] / c;
    float l[NCLSV];
    float mx = -1e30f;
    for (int k = 0; k < NCLSV; ++k) {
        float acc = fc_b[k];
        for (int j = 0; j < C2V; ++j) acc += p[j] * fc_w[j * NCLSV + k];
        l[k] = acc;
        mx = fmaxf(mx, acc);
    }
    float s = 0.f;
    for (int k = 0; k < NCLSV; ++k) s += expf(l[k] - mx);
    float lse = mx + logf(s);
    for (int k = 0; k < NCLSV; ++k) out[g * NCLSV + k] = l[k] - lse;
}

extern "C" void kernel_launch(void* const* d_in, const int* in_sizes, int n_in,
                              void* d_out, int out_size, void* d_ws, size_t ws_size,
                              hipStream_t stream) {
    const float* x = (const float*)d_in[0];
    const int* ei = (const int*)d_in[1];
    const int* batch = (const int*)d_in[2];
    const float* W1 = (const float*)d_in[3];
    const float* att_src1 = (const float*)d_in[4];
    const float* att_dst1 = (const float*)d_in[5];
    const float* b1 = (const float*)d_in[6];
    const float* W2 = (const float*)d_in[7];
    const float* att_src2 = (const float*)d_in[8];
    const float* att_dst2 = (const float*)d_in[9];
    const float* b2 = (const float*)d_in[10];
    const float* fc_w = (const float*)d_in[11];
    const float* fc_b = (const float*)d_in[12];
    float* out = (float*)d_out;

    int N = in_sizes[0] / 256;
    int E = in_sizes[1] / 2;
    int EE = E + N;
    int NB = (N + 255) >> 8;

    float* ws = (float*)d_ws;
    size_t off = 0;
    int* gcur = (int*)(ws + off);      off += 256;   // zeroed each call
    int* bcnt = (int*)(ws + off);      off += 256;   // zeroed each call
    size_t zTot = off;
    int* bucketoff = (int*)(ws + off); off += 257;
    float* pooled = ws + off;          off += (size_t)GV * C2V;
    float* cnt = ws + off;             off += (size_t)GV;
    int* rowoff = (int*)(ws + off);    off += (size_t)N + 1;
    int* bbuf = (int*)(ws + off);      off += (size_t)EE;
    int* ssrc = (int*)(ws + off);      off += (size_t)EE;
    __hip_bfloat16* h1b = (__hip_bfloat16*)(ws + off); off += (size_t)32 * N;  // 64*N bf16
    float* as1 = ws + off;             off += (size_t)4 * N;
    float* ad1 = ws + off;             off += (size_t)4 * N;
    float* h2 = ws + off;              off += (size_t)64 * N;   // fp32, reused as h3
    __hip_bfloat16* t2b = (__hip_bfloat16*)(ws + off); off += (size_t)16 * N;  // 32*N bf16
    float* as2 = ws + off;             off += (size_t)N;
    float* ad2 = ws + off;             off += (size_t)N;
    float* h3 = h2;

    // zero bucket cursors/counts (replay-safe)
    zero_kernel<<<2, 256, 0, stream>>>((int*)ws, (int)zTot);

    // layer-1 linear + attention dots
    gemm1_kernel<<<(N + 15) / 16, 256, 0, stream>>>(x, W1, att_src1, att_dst1, h1b, as1, ad1, N);

    // CSR build (dst-sorted)
    bucketPre_kernel<<<1024, 256, 0, stream>>>(ei, E, EE, bcnt);
    bscan_kernel<<<1, 256, 0, stream>>>(bcnt, bucketoff, rowoff, N, EE);
    bucketA_kernel<<<1024, 256, 0, stream>>>(ei, E, EE, bucketoff, gcur, bbuf);
    bucketB_kernel<<<NB, 256, 0, stream>>>(bucketoff, bbuf, rowoff, ssrc, N);

    // fused layer-1 edge softmax + gather + bias + ELU
    gat1_kernel<<<(N + 3) / 4, 256, 0, stream>>>(rowoff, ssrc, as1, ad1, h1b, b1, h2, N);

    // layer-2 linear + attention dots
    gemm2_kernel<<<(N + 7) / 8, 256, 0, stream>>>(h2, W2, att_src2, att_dst2, t2b, as2, ad2, N);

    // fused layer-2 edge softmax + gather + bias + ELU
    gat2_kernel<<<(N + 3) / 4, 256, 0, stream>>>(rowoff, ssrc, as2, ad2, t2b, b2, h3, N);

    // pooling + FC + log_softmax
    pool_kernel<<<GV, 256, 0, stream>>>(h3, batch, pooled, cnt, N);
    final_kernel<<<1, 64, 0, stream>>>(pooled, cnt, fc_w, fc_b, out);
}